// Round 10
// baseline (1018.690 us; speedup 1.0000x reference)
//
#include <hip/hip_runtime.h>
#include <math.h>

typedef _Float16 f16;
typedef _Float16 f16x4 __attribute__((ext_vector_type(4)));
typedef _Float16 f16x8 __attribute__((ext_vector_type(8)));
typedef float f32x4 __attribute__((ext_vector_type(4)));

#define DEV static __device__ __forceinline__

// ---------------- workspace layout (byte offsets; all 256-aligned) ----------------
// persistent region
#define OFF_X16    ((size_t)0)            // x16 38400x768 f16 (dead after ux GEMM -> tail overlays)
#define OFF_UX     ((size_t)58982400)     // ux16 38400x2048 f16 (n-major rows n*30+s, permuted cols)
#define OFF_OUTS   ((size_t)216268800)    // outs16 38400x512 f16
#define OFF_WD     ((size_t)255590400)    // Wd16 512x512
#define OFF_WALLP  ((size_t)256114688)    // Wall16 permuted 2048x512
#define OFF_UP     ((size_t)258211840)    // Uall16 permuted 2048x768
#define OFF_W2     ((size_t)261357568)    // A1_W2 512x512
#define OFF_WIHP   ((size_t)261881856)    // Wih16 permuted 2048x512
#define OFF_WHHP   ((size_t)263979008)    // Whh16 permuted 2048x512
#define OFF_A2W1C  ((size_t)266076160)    // A2_W1 512x512
#define OFF_A2W2C  ((size_t)266600448)    // A2_W2 512x512
#define OFF_L3WC   ((size_t)267124736)    // lin3 256x512
#define OFF_BALLP  ((size_t)267386880)    // permuted Wall_b+Uall_b 2048 f32
#define OFF_BIHP   ((size_t)267395072)    // permuted bih+bhh 2048 f32
#define OFF_H16    ((size_t)267403264)    // h16 ping-pong 2x 1280x512 f16
#define OFF_C16    ((size_t)270024704)    // c16 ping-pong
#define OFF_C32    ((size_t)272646144)    // c32 ping-pong 2x 1280x512 f32
#define WS_NEED    ((size_t)277889024)
// tail region overlays X16 (x16 dead after ux GEMM; writes happen after ux)
#define OFF_SCORE  ((size_t)0)            // 38400 f32
#define OFF_W1L    ((size_t)153600)       // 5x512 f32
#define OFF_L1O32  ((size_t)163840)       // 1280x512 f32
#define OFF_L1O16  ((size_t)2785280)      // 1280x512 f16
#define OFF_XI2    ((size_t)4096000)      // 1280x2048 f32 (permuted cols, biases included)
#define OFF_C2     ((size_t)14581760)     // ping-pong 2x 256x512 f32
#define OFF_H2     ((size_t)15630336)     // ping-pong 2x 256x512 f16
#define OFF_L2O32  ((size_t)16154624)     // 1280x512 f32
#define OFF_L2O16  ((size_t)18776064)     // f16
#define OFF_U2     ((size_t)20086784)     // 1280x512 f32
#define OFF_V2     ((size_t)22708224)     // 256x512 f32
#define OFF_CTX16  ((size_t)23232512)     // 256x512 f16
#define OFF_H3     ((size_t)23494656)     // 256x256 f32
#define OFF_TFT    ((size_t)23756800)     // tft[s][r] 30x1280 f32 (written after ux)

DEV float sigf(float x) { return 1.f / (1.f + __expf(-x)); }
DEV float tanhfast(float x) { float e = __expf(2.f * x); return 1.f - 2.f / (e + 1.f); }
// permuted col c' -> original row g*512+h, g=(c'>>4)&3, h=(c'>>6)*16+(c'&15)
DEV int permrow(int c) { return (((c >> 4) & 3) << 9) | ((c >> 6) << 4) | (c & 15); }

DEV void gload16(const f16* g, f16x8* lds) {
  __builtin_amdgcn_global_load_lds((const __attribute__((address_space(1))) void*)g,
                                   (__attribute__((address_space(3))) void*)lds, 16, 0, 0);
}

// ---------------- 128x128 fp16 MFMA GEMM core (counted-vmcnt 2-barrier, 4 waves) ----------------
DEV void gemm_core(const f16* __restrict__ A, const f16* __restrict__ Bt, int K,
                   int rowBase, int colBase, f16x8* sh, f32x4 (&acc)[4][4]) {
  const int t = threadIdx.x, lane = t & 63, w = t >> 6;
  const int wr = (w >> 1) * 64, wc = (w & 1) * 64;
  const f16* Arow = A + (size_t)rowBase * K;
  const f16* Brow = Bt + (size_t)colBase * K;
  auto stage = [&](f16x8* dstBase, const f16* src, int k0) {
#pragma unroll
    for (int i = 0; i < 4; ++i) {
      int c = i * 256 + t; int r = c >> 3; int cc = (c & 7) ^ (r & 7);
      gload16(src + (size_t)r * K + (k0 + cc * 8), dstBase + i * 256 + (t & 192));
    }
  };
  stage(sh, Arow, 0);
  stage(sh + 2048, Brow, 0);
  const int nk = K >> 6;
  for (int kt = 0; kt < nk; ++kt) {
    const int cur = kt & 1;
    if (kt + 1 < nk) {
      stage(sh + (cur ^ 1) * 1024, Arow, (kt + 1) * 64);
      stage(sh + 2048 + (cur ^ 1) * 1024, Brow, (kt + 1) * 64);
      asm volatile("s_waitcnt vmcnt(8)" ::: "memory");
    } else {
      asm volatile("s_waitcnt vmcnt(0)" ::: "memory");
    }
    __builtin_amdgcn_s_barrier();
    __builtin_amdgcn_sched_barrier(0);
    const f16x8* shA = sh + cur * 1024;
    const f16x8* shB = sh + 2048 + cur * 1024;
    const int rr = lane & 15, chb = lane >> 4;
#pragma unroll
    for (int kk = 0; kk < 2; ++kk) {
      const int ch = kk * 4 + chb;
      f16x8 af[4], bf[4];
#pragma unroll
      for (int m = 0; m < 4; ++m) { int row = wr + m * 16 + rr; af[m] = shA[row * 8 + (ch ^ (row & 7))]; }
#pragma unroll
      for (int n = 0; n < 4; ++n) { int row = wc + n * 16 + rr; bf[n] = shB[row * 8 + (ch ^ (row & 7))]; }
#pragma unroll
      for (int m = 0; m < 4; ++m)
#pragma unroll
        for (int n = 0; n < 4; ++n)
          acc[m][n] = __builtin_amdgcn_mfma_f32_16x16x32_f16(af[m], bf[n], acc[m][n], 0, 0, 0);
    }
    __builtin_amdgcn_sched_barrier(0);
    __builtin_amdgcn_s_barrier();
  }
}

// ---------------- 256x256 fp16 MFMA GEMM core (8 waves; used by k_score2) ----------------
DEV void gemm_core256(const f16* __restrict__ A, const f16* __restrict__ Bt, int K,
                      int rowBase, int colBase, f16x8 (&shA)[2][2048], f16x8 (&shB)[2][2048],
                      f32x4 (&acc)[8][4]) {
  const int t = threadIdx.x, lane = t & 63, w = t >> 6;
  const int wm = w >> 2, wn = w & 3;       // 2 x 4 wave grid; wave owns 128x64
  const f16* Arow = A + (size_t)rowBase * K;
  const f16* Brow = Bt + (size_t)colBase * K;
  auto stage = [&](f16x8* dst, const f16* src, int k0) {
#pragma unroll
    for (int i = 0; i < 4; ++i) {
      int c = i * 512 + t; int r = c >> 3; int cc = (c & 7) ^ (r & 7);
      gload16(src + (size_t)r * K + (k0 + cc * 8), dst + i * 512 + (t & 448));
    }
  };
  stage(shA[0], Arow, 0);
  stage(shB[0], Brow, 0);
  const int nk = K >> 6;
  for (int kt = 0; kt < nk; ++kt) {
    const int cur = kt & 1;
    if (kt + 1 < nk) {
      stage(shA[cur ^ 1], Arow, (kt + 1) * 64);
      stage(shB[cur ^ 1], Brow, (kt + 1) * 64);
      asm volatile("s_waitcnt vmcnt(8)" ::: "memory");
    } else {
      asm volatile("s_waitcnt vmcnt(0)" ::: "memory");
    }
    __builtin_amdgcn_s_barrier();
    __builtin_amdgcn_sched_barrier(0);
    const f16x8* pA = shA[cur];
    const f16x8* pB = shB[cur];
    const int rr = lane & 15, chb = lane >> 4;
#pragma unroll
    for (int kk = 0; kk < 2; ++kk) {
      const int ch = kk * 4 + chb;
      f16x8 bf[4];
#pragma unroll
      for (int n = 0; n < 4; ++n) { int row = wn * 64 + n * 16 + rr; bf[n] = pB[row * 8 + (ch ^ (row & 7))]; }
#pragma unroll
      for (int m = 0; m < 8; ++m) {
        int row = wm * 128 + m * 16 + rr;
        f16x8 af = pA[row * 8 + (ch ^ (row & 7))];
#pragma unroll
        for (int n = 0; n < 4; ++n)
          acc[m][n] = __builtin_amdgcn_mfma_f32_16x16x32_f16(af, bf[n], acc[m][n], 0, 0, 0);
      }
    }
    __builtin_amdgcn_sched_barrier(0);
    __builtin_amdgcn_s_barrier();
  }
}

// attn1 score on the 256^2 core: score[r] += sum_c V[c]*tanh(gemm + W2b[c] + w1l[d][c])
__global__ __launch_bounds__(512, 1) void k_score2(const f16* __restrict__ outs, const f16* __restrict__ W2t,
    const float* __restrict__ W2b, const float* __restrict__ w1l, const float* __restrict__ V,
    float* __restrict__ score) {
  __shared__ f16x8 shA[2][2048];
  __shared__ f16x8 shB[2][2048];
  __shared__ float sacc[256];
  const int rb = blockIdx.y * 256, cb = blockIdx.x * 256;
  f32x4 acc[8][4] = {};
  gemm_core256(outs, W2t, 512, rb, cb, shA, shB, acc);
  const int t = threadIdx.x, lane = t & 63, w = t >> 6;
  const int wm = w >> 2, wn = w & 3;
  const int ec = lane & 15, er = (lane >> 4) * 4;
  if (t < 256) sacc[t] = 0.f;
  __syncthreads();
#pragma unroll
  for (int m = 0; m < 8; ++m)
#pragma unroll
    for (int j = 0; j < 4; ++j) {
      const int lr = wm * 128 + m * 16 + er + j;
      const int r = rb + lr;
      const int d = (r / 30) >> 8;
      float p = 0.f;
#pragma unroll
      for (int n = 0; n < 4; ++n) {
        const int c = cb + wn * 64 + n * 16 + ec;
        p += V[c] * tanhfast(acc[m][n][j] + W2b[c] + w1l[d * 512 + c]);
      }
      p += __shfl_xor(p, 1); p += __shfl_xor(p, 2); p += __shfl_xor(p, 4); p += __shfl_xor(p, 8);
      if (ec == 0) atomicAdd(&sacc[lr], p);
    }
  __syncthreads();
  if (t < 256) atomicAdd(&score[rb + t], sacc[t]);
}

// ---------------- generic bias/act GEMM wrapper (2D grid, 128^2) ----------------
template <int ACT, bool O32, bool O16>
__global__ __launch_bounds__(256, 2) void k_gemm(const f16* __restrict__ A, const f16* __restrict__ Bt,
                                                 int K, int N, const float* __restrict__ bias,
                                                 float* __restrict__ C32, f16* __restrict__ C16) {
  __shared__ f16x8 sh[4096];
  const int rb = blockIdx.y * 128, cb = blockIdx.x * 128;
  f32x4 acc[4][4] = {};
  gemm_core(A, Bt, K, rb, cb, sh, acc);
  const int t = threadIdx.x, lane = t & 63, w = t >> 6;
  const int wr = (w >> 1) * 64, wc = (w & 1) * 64, ec = lane & 15, er = (lane >> 4) * 4;
#pragma unroll
  for (int m = 0; m < 4; ++m)
#pragma unroll
    for (int n = 0; n < 4; ++n) {
      const int c = cb + wc + n * 16 + ec;
      const float bv = bias ? bias[c] : 0.f;
#pragma unroll
      for (int j = 0; j < 4; ++j) {
        const int r = rb + wr + m * 16 + er + j;
        float v = acc[m][n][j] + bv;
        if (ACT == 3) v = fmaxf(v, 0.f);
        if (O32) C32[(size_t)r * N + c] = v;
        if (O16) C16[(size_t)r * N + c] = (f16)v;
      }
    }
}

// ---------------- fused TimeLSTM step (R6-verified; n-major ux rows n*30+s) ----------------
__global__ __launch_bounds__(256, 1) void k_stepf(
    const f16* __restrict__ hin, const f16* __restrict__ cin16, const float* __restrict__ cin32,
    const f16* __restrict__ Wallp, const f16* __restrict__ Wd16,
    const f16* __restrict__ ux, const float* __restrict__ ballp, const float* __restrict__ Wd_b,
    const float* __restrict__ tft,
    float* __restrict__ cout32, f16* __restrict__ cout16, f16* __restrict__ hout,
    f16* __restrict__ outs, int s) {
  __shared__ f16x8 shA[2048];
  __shared__ f16x8 shB[2048];
  __shared__ f16x8 shC[2048];
  __shared__ f16x8 shD[512];
  __shared__ f16x8 shU[2048];   // ux slice 128x128 f16, swizzled
  __shared__ f16x8 shE[1024];   // c32 slice 128x32 f32, swizzled
  const int t = threadIdx.x, lane = t & 63, w = t >> 6;
  const int rb = ((int)blockIdx.x >> 4) * 128;
  const int cg = (int)blockIdx.x & 15;
  const int wr = (w >> 1) * 64, wc = (w & 1) * 64;
  const int rr = lane & 15, chb = lane >> 4;
  const int ec = lane & 15, er = (lane >> 4) * 4;
  const int h = cg * 32 + (w & 1) * 16 + ec;
  const int hcol = (w & 1) * 16 + ec;
  const f16* Ah = hin + (size_t)rb * 512;
  const f16* Ac = cin16 + (size_t)rb * 512;
  const f16* Bw = Wallp + (size_t)cg * 128 * 512;
  const f16* Bd = Wd16 + (size_t)cg * 32 * 512;
  float bW[4];
#pragma unroll
  for (int n = 0; n < 4; ++n) bW[n] = ballp[cg * 128 + wc + n * 16 + ec];
  const float bD = Wd_b[h];
  const f16* shUf = (const f16*)shU;
  const float* shEf = (const float*)shE;
  const int kbase = (wc >> 3) + (ec >> 3);   // ux col-chunk base for this thread
  f32x4 acc[4][4] = {};
  f32x4 acc2[4] = {};

  auto stage128 = [&](f16x8* dstBase, const f16* src, int k0) {
#pragma unroll
    for (int i = 0; i < 4; ++i) {
      int c = i * 256 + t; int r = c >> 3; int cc = (c & 7) ^ (r & 7);
      gload16(src + (size_t)r * 512 + (k0 + cc * 8), dstBase + i * 256 + (t & 192));
    }
  };
  auto stage32 = [&](f16x8* dstBase, const f16* src, int k0) {
    const int r = t >> 3; const int cc = (t & 7) ^ (r & 7);
    gload16(src + (size_t)r * 512 + (k0 + cc * 8), dstBase + (t & 192));
  };
  auto stageU = [&]() {   // n-major: row (rb+lr)*30+s, swizzle chunk ^= ((lr>>2)&3)<<1
#pragma unroll
    for (int i = 0; i < 8; ++i) {
      int c = i * 256 + t; int lr = c >> 4; int k = c & 15;
      int klog = k ^ (((lr >> 2) & 3) << 1);
      gload16(ux + ((size_t)(rb + lr) * 30 + s) * 2048 + cg * 128 + klog * 8,
              shU + i * 256 + (t & 192));
    }
  };
  auto stageE = [&]() {  // swizzle: chunk ^= ((lr>>2)&1)<<2
#pragma unroll
    for (int i = 0; i < 4; ++i) {
      int c = i * 256 + t; int lr = c >> 3; int k = c & 7;
      int klog = k ^ (((lr >> 2) & 1) << 2);
      gload16((const f16*)(cin32 + (size_t)(rb + lr) * 512 + cg * 32 + klog * 4),
              shE + i * 256 + (t & 192));
    }
  };

  if (s == 0) {
    stageU();
    stageE();
    asm volatile("s_waitcnt vmcnt(0)" ::: "memory");
    __builtin_amdgcn_s_barrier();
  } else {
    stage128(shA, Ah, 0);
    stage128(shB, Bw, 0);
    stage128(shC, Ac, 0);
    stage32(shD, Bd, 0);
    stageU();
    stageE();
    for (int kt = 0; kt < 8; ++kt) {
      const int cur = kt & 1;
      if (kt < 7) {
        stage128(shA + (cur ^ 1) * 1024, Ah, (kt + 1) * 64);
        stage128(shB + (cur ^ 1) * 1024, Bw, (kt + 1) * 64);
        stage128(shC + (cur ^ 1) * 1024, Ac, (kt + 1) * 64);
        stage32(shD + (cur ^ 1) * 256, Bd, (kt + 1) * 64);
        asm volatile("s_waitcnt vmcnt(13)" ::: "memory");
      } else {
        asm volatile("s_waitcnt vmcnt(0)" ::: "memory");
      }
      __builtin_amdgcn_s_barrier();
      __builtin_amdgcn_sched_barrier(0);
      const f16x8* pA = shA + cur * 1024;
      const f16x8* pB = shB + cur * 1024;
      const f16x8* pC = shC + cur * 1024;
      const f16x8* pD = shD + cur * 256;
#pragma unroll
      for (int kk = 0; kk < 2; ++kk) {
        const int ch = kk * 4 + chb;
        f16x8 af[4], bf[4], cf[4], df;
#pragma unroll
        for (int m = 0; m < 4; ++m) {
          const int row = wr + m * 16 + rr;
          af[m] = pA[row * 8 + (ch ^ (row & 7))];
          cf[m] = pC[row * 8 + (ch ^ (row & 7))];
        }
#pragma unroll
        for (int n = 0; n < 4; ++n) { const int row = wc + n * 16 + rr; bf[n] = pB[row * 8 + (ch ^ (row & 7))]; }
        { const int row = (w & 1) * 16 + rr; df = pD[row * 8 + (ch ^ (row & 7))]; }
#pragma unroll
        for (int m = 0; m < 4; ++m) {
#pragma unroll
          for (int n = 0; n < 4; ++n)
            acc[m][n] = __builtin_amdgcn_mfma_f32_16x16x32_f16(af[m], bf[n], acc[m][n], 0, 0, 0);
          acc2[m] = __builtin_amdgcn_mfma_f32_16x16x32_f16(cf[m], df, acc2[m], 0, 0, 0);
        }
      }
      __builtin_amdgcn_sched_barrier(0);
      __builtin_amdgcn_s_barrier();
    }
  }

  // epilogue: full cell update; ux/c32 from swizzled LDS, tf from tft (coalesced). (verified R5/R6/R7)
#pragma unroll
  for (int m = 0; m < 4; ++m)
#pragma unroll
    for (int j = 0; j < 4; ++j) {
      const int lr = wr + m * 16 + er + j;
      const int r = rb + lr;
      const float tv = tft[s * 1280 + r];
      const int sU = ((lr >> 2) & 3) << 1;
      const float u0 = (float)shUf[(lr * 16 + ((kbase + 0) ^ sU)) * 8 + (ec & 7)];
      const float u1 = (float)shUf[(lr * 16 + ((kbase + 2) ^ sU)) * 8 + (ec & 7)];
      const float u2v = (float)shUf[(lr * 16 + ((kbase + 4) ^ sU)) * 8 + (ec & 7)];
      const float u3 = (float)shUf[(lr * 16 + ((kbase + 6) ^ sU)) * 8 + (ec & 7)];
      const float p0 = acc[m][0][j] + bW[0] + u0;
      const float p1 = acc[m][1][j] + bW[1] + u1;
      const float p2 = acc[m][2][j] + bW[2] + u2v;
      const float p3 = acc[m][3][j] + bW[3] + u3;
      const float f = sigf(p0), i = sigf(p1), o = sigf(p2), ct = sigf(p3);
      const float cs = tanhfast(acc2[m][j] + bD);
      const int sE = ((lr >> 2) & 1) << 2;
      const float c_old = shEf[(lr * 8 + ((hcol >> 2) ^ sE)) * 4 + (hcol & 3)];
      const float cadj = c_old - cs + cs * tv;
      const float cn = f * cadj + i * ct;
      cout32[(size_t)r * 512 + h] = cn;
      cout16[(size_t)r * 512 + h] = (f16)cn;
      hout[(size_t)r * 512 + h] = (f16)(o * tanhfast(cn));
      outs[((size_t)r * 30 + s) * 512 + h] = (f16)o;
    }
}

// ---------------- fused lstm2 step ----------------
__global__ __launch_bounds__(256, 2) void k_l2step(const f16* __restrict__ hin, const f16* __restrict__ Whhp,
    const float* __restrict__ xi2, const float* __restrict__ cin, float* __restrict__ cout,
    f16* __restrict__ hout, float* __restrict__ l2o32, f16* __restrict__ l2o16, int ts) {
  __shared__ f16x8 sh[4096];
  const int rb = (blockIdx.x >> 4) * 128, cg = blockIdx.x & 15;
  f32x4 acc[4][4] = {};
  gemm_core(hin, Whhp, 512, rb, cg * 128, sh, acc);
  const int t = threadIdx.x, lane = t & 63, w = t >> 6;
  const int wr = (w >> 1) * 64, wc = (w & 1) * 64, ec = lane & 15, er = (lane >> 4) * 4;
  const int h = cg * 32 + (w & 1) * 16 + ec;
#pragma unroll
  for (int m = 0; m < 4; ++m)
#pragma unroll
    for (int j = 0; j < 4; ++j) {
      const int r = rb + wr + m * 16 + er + j;
      const size_t xb = ((size_t)r * 5 + ts) * 2048 + cg * 128 + wc + ec;
      const float p0 = acc[m][0][j] + xi2[xb];
      const float p1 = acc[m][1][j] + xi2[xb + 16];
      const float p2 = acc[m][2][j] + xi2[xb + 32];
      const float p3 = acc[m][3][j] + xi2[xb + 48];
      const float ii = sigf(p0), ff = sigf(p1), gg = tanhfast(p2), oo = sigf(p3);
      const float cn = ff * cin[(size_t)r * 512 + h] + ii * gg;
      const float hn = oo * tanhfast(cn);
      cout[(size_t)r * 512 + h] = cn;
      hout[(size_t)r * 512 + h] = (f16)hn;
      const size_t ob = ((size_t)r * 5 + ts) * 512 + h;
      l2o32[ob] = hn;
      l2o16[ob] = (f16)hn;
    }
}

// w1last[d] = A1_W1 @ outs[d, B-1, len-1] + b
__global__ __launch_bounds__(256) void k_w1last(const f16* __restrict__ outs, const int* __restrict__ lens,
                                                const float* __restrict__ W1, const float* __restrict__ W1b,
                                                float* __restrict__ w1l) {
  __shared__ float lastv[512];
  const int d = blockIdx.x;
  const int idx = lens[255 * 5 + d] - 1;
  const size_t row = ((size_t)(d * 256 + 255) * 30 + idx) * 512;
  for (int h = threadIdx.x; h < 512; h += 256) lastv[h] = (float)outs[row + h];
  __syncthreads();
  for (int h = threadIdx.x; h < 512; h += 256) {
    const float* wr = W1 + (size_t)h * 512;
    float p = W1b[h];
    for (int k = 0; k < 512; ++k) p += lastv[k] * wr[k];
    w1l[d * 512 + h] = p;
  }
}

// attn1 softmax + weighted sum
__global__ __launch_bounds__(256) void k_attn1(const float* __restrict__ score, const f16* __restrict__ outs,
                                               const int* __restrict__ lens,
                                               float* __restrict__ l1o32, f16* __restrict__ l1o16) {
  __shared__ float saw[32];
  const int n = blockIdx.x;
  const int d = n >> 8, b = n & 255;
  const int len = lens[b * 5 + d];
  const int t = threadIdx.x, lane = t & 63, w = t >> 6;
  if (w == 0) {
    const bool valid = lane < len;
    float sc = valid ? score[(size_t)n * 30 + lane] : -INFINITY;
    float mx = sc;
#pragma unroll
    for (int off = 32; off > 0; off >>= 1) mx = fmaxf(mx, __shfl_xor(mx, off));
    float e = valid ? __expf(sc - mx) : 0.f;
    float sm = e;
#pragma unroll
    for (int off = 32; off > 0; off >>= 1) sm += __shfl_xor(sm, off);
    if (lane < 30) saw[lane] = e / sm;
  }
  __syncthreads();
  for (int h = t; h < 512; h += 256) {
    float acc = 0.f;
    for (int s = 0; s < len; ++s) acc += saw[s] * (float)outs[((size_t)n * 30 + s) * 512 + h];
    const size_t o = ((size_t)b * 5 + d) * 512 + h;
    l1o32[o] = acc;
    l1o16[o] = (f16)acc;
  }
}

// merged u2/v2 GEMMs for attn2
__global__ __launch_bounds__(256, 2) void k_uv(const f16* __restrict__ l2o16, const f16* __restrict__ A2W2c,
    const f16* __restrict__ h2fin, const f16* __restrict__ A2W1c,
    const float* __restrict__ bu, const float* __restrict__ bv,
    float* __restrict__ u2, float* __restrict__ v2) {
  __shared__ f16x8 sh[4096];
  const int bid = blockIdx.x;
  const f16* A; const f16* B; const float* bias; float* out; int rb, cb;
  if (bid < 40) { A = l2o16; B = A2W2c; bias = bu; out = u2; rb = (bid >> 2) * 128; cb = (bid & 3) * 128; }
  else { int b2 = bid - 40; A = h2fin; B = A2W1c; bias = bv; out = v2; rb = (b2 >> 2) * 128; cb = (b2 & 3) * 128; }
  f32x4 acc[4][4] = {};
  gemm_core(A, B, 512, rb, cb, sh, acc);
  const int t = threadIdx.x, lane = t & 63, w = t >> 6;
  const int wr = (w >> 1) * 64, wc = (w & 1) * 64, ec = lane & 15, er = (lane >> 4) * 4;
#pragma unroll
  for (int m = 0; m < 4; ++m)
#pragma unroll
    for (int n = 0; n < 4; ++n) {
      const int c = cb + wc + n * 16 + ec;
      const float bvv = bias[c];
#pragma unroll
      for (int j = 0; j < 4; ++j) out[(size_t)(rb + wr + m * 16 + er + j) * 512 + c] = acc[m][n][j] + bvv;
    }
}

// attn2 over D=5 days
__global__ __launch_bounds__(256) void k_attn2(const float* __restrict__ u2, const float* __restrict__ v2,
                                               const float* __restrict__ l2o, const float* __restrict__ V2,
                                               const float* __restrict__ V2b, f16* __restrict__ ctx16) {
  __shared__ float ssc[8];
  __shared__ float saw[8];
  const int b = blockIdx.x;
  const int t = threadIdx.x, lane = t & 63, w = t >> 6;
  for (int tt = w; tt < 5; tt += 4) {
    const float* ur = u2 + ((size_t)b * 5 + tt) * 512;
    const float* vr = v2 + (size_t)b * 512;
    float p = 0.f;
#pragma unroll
    for (int j = 0; j < 8; ++j) { int h = lane * 8 + j; p += V2[h] * tanhfast(ur[h] + vr[h]); }
#pragma unroll
    for (int off = 32; off > 0; off >>= 1) p += __shfl_down(p, off);
    if (lane == 0) ssc[tt] = p + V2b[0];
  }
  __syncthreads();
  if (w == 0) {
    const bool valid = lane < 5;
    float sc = valid ? ssc[lane] : -INFINITY;
    float mx = sc;
#pragma unroll
    for (int off = 32; off > 0; off >>= 1) mx = fmaxf(mx, __shfl_xor(mx, off));
    float e = valid ? __expf(sc - mx) : 0.f;
    float sm = e;
#pragma unroll
    for (int off = 32; off > 0; off >>= 1) sm += __shfl_xor(sm, off);
    if (valid) saw[lane] = e / sm;
  }
  __syncthreads();
  for (int h = t; h < 512; h += 256) {
    float a = 0.f;
#pragma unroll
    for (int tt = 0; tt < 5; ++tt) a += saw[tt] * l2o[((size_t)b * 5 + tt) * 512 + h];
    ctx16[(size_t)b * 512 + h] = (f16)a;
  }
}

// final: out = h3 @ lin4^T + b4
__global__ __launch_bounds__(256) void k_final(const float* __restrict__ h3, const float* __restrict__ W4,
                                               const float* __restrict__ b4, float* __restrict__ out) {
  const int idx = blockIdx.x * 256 + threadIdx.x;
  const int b = idx >> 1, o = idx & 1;
  const float* hr = h3 + b * 256;
  const float* wr = W4 + o * 256;
  float p = b4[o];
  for (int j = 0; j < 256; ++j) p += hr[j] * wr[j];
  out[idx] = p;
}

// ---------------- prep kernels ----------------
// cast sentence_feats to n-major x16 rows m=(d*256+b)*30+s  (R6-verified)
__global__ __launch_bounds__(256) void k_castx(const float* __restrict__ sf, f16* __restrict__ x16) {
  const int total = 7372800;  // 38400*768/4
  for (int e = blockIdx.x * 256 + threadIdx.x; e < total; e += gridDim.x * 256) {
    const int row = e / 192, k = e - row * 192;
    const int b = row / 150, rem = row - b * 150;
    const int d = rem / 30, s = rem - d * 30;
    const int orow = (d * 256 + b) * 30 + s;
    const float4 v = ((const float4*)sf)[e];
    f16x4 o = {(f16)v.x, (f16)v.y, (f16)v.z, (f16)v.w};
    ((f16x4*)x16)[(size_t)orow * 192 + k] = o;
  }
}

// merged weight cast (+optional gate permutation)  (R7-verified)
struct WPArgs { const float* src[9]; f16* dst[9]; int k4[9]; int cnt4[9]; int perm[9]; };
__global__ __launch_bounds__(256) void k_castwp(WPArgs a) {
  int g = blockIdx.x * 256 + threadIdx.x;
#pragma unroll
  for (int si = 0; si < 9; ++si) {
    if (g < a.cnt4[si]) {
      const int K4 = a.k4[si];
      const int c = g / K4, k = g - c * K4;
      const int srow = a.perm[si] ? permrow(c) : c;
      const float4 v = ((const float4*)a.src[si])[(size_t)srow * K4 + k];
      f16x4 o = {(f16)v.x, (f16)v.y, (f16)v.z, (f16)v.w};
      ((f16x4*)a.dst[si])[(size_t)c * K4 + k] = o;
      return;
    }
    g -= a.cnt4[si];
  }
}

// runs AFTER the ux GEMM (tft/score overlay the dead x16 region)  (R6/R7-verified)
__global__ __launch_bounds__(256) void k_zero(f16* h16a, f16* c16a, float* c32a,
    float* ballp, float* bihp, const float* Wall_b, const float* Uall_b,
    const float* bih, const float* bhh, float* tft, const float* tf,
    float* score, const float* Vb, f16* h2a, float* c2a) {
  const int i = blockIdx.x * 256 + threadIdx.x;
  if (i < 655360) { h16a[i] = (f16)0.f; c16a[i] = (f16)0.f; c32a[i] = 0.f; }
  if (i < 2048) {
    const int p = permrow(i);
    ballp[i] = Wall_b[p] + Uall_b[p];
    bihp[i] = bih[p] + bhh[p];
  }
  if (i < 38400) {
    const int s = i / 1280, r = i - s * 1280;
    const int d = r >> 8, b = r & 255;
    tft[i] = tf[((size_t)b * 5 + d) * 30 + s];
    score[i] = Vb[0];
  }
  if (i < 131072) { h2a[i] = (f16)0.f; c2a[i] = 0.f; }
}

// ---------------- launch ----------------
extern "C" void kernel_launch(void* const* d_in, const int* in_sizes, int n_in,
                              void* d_out, int out_size, void* d_ws, size_t ws_size,
                              hipStream_t stream) {
  const float* sf     = (const float*)d_in[0];
  const float* tf     = (const float*)d_in[1];
  const int*   lens   = (const int*)d_in[2];
  const float* Wd_w   = (const float*)d_in[3];
  const float* Wd_b   = (const float*)d_in[4];
  const float* Wall_w = (const float*)d_in[5];
  const float* Wall_b = (const float*)d_in[6];
  const float* Uall_w = (const float*)d_in[7];
  const float* Uall_b = (const float*)d_in[8];
  const float* A1W1   = (const float*)d_in[9];
  const float* A1W1b  = (const float*)d_in[10];
  const float* A1W2   = (const float*)d_in[11];
  const float* A1W2b  = (const float*)d_in[12];
  const float* A1V    = (const float*)d_in[13];
  const float* A1Vb   = (const float*)d_in[14];
  const float* Wih    = (const float*)d_in[15];
  const float* Whh    = (const float*)d_in[16];
  const float* bih    = (const float*)d_in[17];
  const float* bhh    = (const float*)d_in[18];
  const float* A2W1   = (const float*)d_in[19];
  const float* A2W1b  = (const float*)d_in[20];
  const float* A2W2   = (const float*)d_in[21];
  const float* A2W2b  = (const float*)d_in[22];
  const float* A2V    = (const float*)d_in[23];
  const float* A2Vb   = (const float*)d_in[24];
  const float* L3w    = (const float*)d_in[25];
  const float* L3b    = (const float*)d_in[26];
  const float* L4w    = (const float*)d_in[27];
  const float* L4b    = (const float*)d_in[28];

  if (ws_size < WS_NEED) return;
  char* ws = (char*)d_ws;
  f16*   x16    = (f16*)(ws + OFF_X16);
  f16*   ux16   = (f16*)(ws + OFF_UX);
  f16*   outs16 = (f16*)(ws + OFF_OUTS);
  f16*   Wd16   = (f16*)(ws + OFF_WD);
  f16*   Wallp  = (f16*)(ws + OFF_WALLP);
  f16*   U16p   = (f16*)(ws + OFF_UP);
  f16*   W216   = (f16*)(ws + OFF_W2);
  f16*   Wihp   = (f16*)(ws + OFF_WIHP);
  f16*   Whhp   = (f16*)(ws + OFF_WHHP);
  f16*   A2W116 = (f16*)(ws + OFF_A2W1C);
  f16*   A2W216 = (f16*)(ws + OFF_A2W2C);
  f16*   L316   = (f16*)(ws + OFF_L3WC);
  float* ballp  = (float*)(ws + OFF_BALLP);
  float* bihp   = (float*)(ws + OFF_BIHP);
  f16*   h16b[2]  = {(f16*)(ws + OFF_H16), (f16*)(ws + OFF_H16 + 1310720)};
  f16*   c16b[2]  = {(f16*)(ws + OFF_C16), (f16*)(ws + OFF_C16 + 1310720)};
  float* c32b[2]  = {(float*)(ws + OFF_C32), (float*)(ws + OFF_C32 + 2621440)};
  float* score  = (float*)(ws + OFF_SCORE);
  float* w1l    = (float*)(ws + OFF_W1L);
  float* l1o32  = (float*)(ws + OFF_L1O32);
  f16*   l1o16  = (f16*)(ws + OFF_L1O16);
  float* xi2    = (float*)(ws + OFF_XI2);
  float* c2b[2] = {(float*)(ws + OFF_C2), (float*)(ws + OFF_C2 + 524288)};
  f16*   h2b[2] = {(f16*)(ws + OFF_H2), (f16*)(ws + OFF_H2 + 262144)};
  float* l2o32  = (float*)(ws + OFF_L2O32);
  f16*   l2o16  = (f16*)(ws + OFF_L2O16);
  float* u2     = (float*)(ws + OFF_U2);
  float* v2     = (float*)(ws + OFF_V2);
  f16*   ctx16  = (f16*)(ws + OFF_CTX16);
  float* h3     = (float*)(ws + OFF_H3);
  float* tft    = (float*)(ws + OFF_TFT);

  // 1. input casts (x16 must stay live for the ux GEMM; tft/score written after)
  k_castx<<<2048, 256, 0, stream>>>(sf, x16);
  WPArgs wa;
  wa.src[0] = Wd_w;   wa.dst[0] = Wd16;   wa.k4[0] = 128; wa.cnt4[0] = 65536;  wa.perm[0] = 0;
  wa.src[1] = A1W2;   wa.dst[1] = W216;   wa.k4[1] = 128; wa.cnt4[1] = 65536;  wa.perm[1] = 0;
  wa.src[2] = A2W1;   wa.dst[2] = A2W116; wa.k4[2] = 128; wa.cnt4[2] = 65536;  wa.perm[2] = 0;
  wa.src[3] = A2W2;   wa.dst[3] = A2W216; wa.k4[3] = 128; wa.cnt4[3] = 65536;  wa.perm[3] = 0;
  wa.src[4] = L3w;    wa.dst[4] = L316;   wa.k4[4] = 128; wa.cnt4[4] = 32768;  wa.perm[4] = 0;
  wa.src[5] = Wall_w; wa.dst[5] = Wallp;  wa.k4[5] = 128; wa.cnt4[5] = 262144; wa.perm[5] = 1;
  wa.src[6] = Uall_w; wa.dst[6] = U16p;   wa.k4[6] = 192; wa.cnt4[6] = 393216; wa.perm[6] = 1;
  wa.src[7] = Wih;    wa.dst[7] = Wihp;   wa.k4[7] = 128; wa.cnt4[7] = 262144; wa.perm[7] = 1;
  wa.src[8] = Whh;    wa.dst[8] = Whhp;   wa.k4[8] = 128; wa.cnt4[8] = 262144; wa.perm[8] = 1;
  k_castwp<<<5760, 256, 0, stream>>>(wa);

  // 2. ux = x @ Uall'^T  (M=38400, N=2048 permuted, K=768) — R6-verified 128^2 core
  k_gemm<0, false, true><<<dim3(16, 300), 256, 0, stream>>>(x16, U16p, 768, 2048, nullptr, nullptr, ux16);

  // 3. state init + tft + score init (x16 now dead)
  k_zero<<<2560, 256, 0, stream>>>(h16b[0], c16b[0], c32b[0], ballp, bihp, Wall_b, Uall_b, bih, bhh,
                                   tft, tf, score, A1Vb, h2b[0], c2b[0]);

  // 4. TimeLSTM recurrence, 30 fused steps (ping-pong state, separate launches)
  for (int s = 0; s < 30; ++s) {
    const int pi = s & 1, po = pi ^ 1;
    k_stepf<<<160, 256, 0, stream>>>(h16b[pi], c16b[pi], c32b[pi], Wallp, Wd16, ux16, ballp, Wd_b, tft,
                                     c32b[po], c16b[po], h16b[po], outs16, s);
  }

  // 5. attn1
  k_w1last<<<5, 256, 0, stream>>>(outs16, lens, A1W1, A1W1b, w1l);
  k_score2<<<dim3(2, 150), 512, 0, stream>>>(outs16, W216, A1W2b, w1l, A1V, score);
  k_attn1<<<1280, 256, 0, stream>>>(score, outs16, lens, l1o32, l1o16);

  // 6. lstm2: xi2 (permuted cols, biases folded), then 5 fused steps
  k_gemm<0, true, false><<<dim3(16, 10), 256, 0, stream>>>(l1o16, Wihp, 512, 2048, bihp, xi2, nullptr);
  for (int ts = 0; ts < 5; ++ts) {
    const int pi = ts & 1, po = pi ^ 1;
    k_l2step<<<32, 256, 0, stream>>>(h2b[pi], Whhp, xi2, c2b[pi], c2b[po], h2b[po], l2o32, l2o16, ts);
  }

  // 7. attn2 (h2 final is buffer 1 after 5 steps)
  k_uv<<<48, 256, 0, stream>>>(l2o16, A2W216, h2b[1], A2W116, A2W2b, A2W1b, u2, v2);
  k_attn2<<<256, 256, 0, stream>>>(u2, v2, l2o32, A2V, A2Vb, ctx16);

  // 8. head
  k_gemm<3, true, false><<<dim3(2, 2), 256, 0, stream>>>(ctx16, L316, 512, 256, L3b, h3, nullptr);
  k_final<<<2, 256, 0, stream>>>(h3, L4w, L4b, (float*)d_out);
}

// Round 11
// 946.875 us; speedup vs baseline: 1.0758x; 1.0758x over previous
//
#include <hip/hip_runtime.h>
#include <math.h>

typedef _Float16 f16;
typedef _Float16 f16x4 __attribute__((ext_vector_type(4)));
typedef _Float16 f16x8 __attribute__((ext_vector_type(8)));
typedef float f32x4 __attribute__((ext_vector_type(4)));

#define DEV static __device__ __forceinline__

// ---------------- workspace layout (byte offsets; all 256-aligned) ----------------
// persistent region
#define OFF_X16    ((size_t)0)            // x16s [s][n][768] f16 (live until launch 27; tail overlays after)
#define OFF_UX     ((size_t)58982400)     // ux16 [s][n][2048] f16 s-major (permuted cols)
#define OFF_OUTS   ((size_t)216268800)    // outs16 38400x512 f16 (n*30+s row layout)
#define OFF_WD     ((size_t)255590400)    // Wd16 512x512
#define OFF_WALLP  ((size_t)256114688)    // Wall16 permuted 2048x512
#define OFF_UP     ((size_t)258211840)    // Uall16 permuted 2048x768
#define OFF_W2     ((size_t)261357568)    // A1_W2 512x512
#define OFF_WIHP   ((size_t)261881856)    // Wih16 permuted 2048x512
#define OFF_WHHP   ((size_t)263979008)    // Whh16 permuted 2048x512
#define OFF_A2W1C  ((size_t)266076160)    // A2_W1 512x512
#define OFF_A2W2C  ((size_t)266600448)    // A2_W2 512x512
#define OFF_L3WC   ((size_t)267124736)    // lin3 256x512
#define OFF_BALLP  ((size_t)267386880)    // permuted Wall_b+Uall_b 2048 f32
#define OFF_BIHP   ((size_t)267395072)    // permuted bih+bhh 2048 f32
#define OFF_H16    ((size_t)267403264)    // h16 ping-pong 2x 1280x512 f16
#define OFF_C16    ((size_t)270024704)    // c16 ping-pong
#define OFF_C32    ((size_t)272646144)    // c32 ping-pong 2x 1280x512 f32
#define OFF_TFTN   ((size_t)277889024)    // tft[s][r] 30x1280 f32 (fresh region)
#define OFF_SCOREN (OFF_TFTN + 153600)    // score 38400 f32 (fresh region)
#define WS_NEED    (OFF_SCOREN + 153600)  // ws >= this proven by R8/R9 executing
// tail region overlays X16 (x16s dead after launch 27; ALL writes below happen after the recurrence)
#define OFF_W1L    ((size_t)153600)       // 5x512 f32
#define OFF_L1O32  ((size_t)163840)       // 1280x512 f32
#define OFF_L1O16  ((size_t)2785280)      // 1280x512 f16
#define OFF_XI2    ((size_t)4096000)      // 1280x2048 f32 (permuted cols, biases included)
#define OFF_C2     ((size_t)14581760)     // ping-pong 2x 256x512 f32   (init by k_init2 AFTER recurrence)
#define OFF_H2     ((size_t)15630336)     // ping-pong 2x 256x512 f16   (init by k_init2 AFTER recurrence)
#define OFF_L2O32  ((size_t)16154624)     // 1280x512 f32
#define OFF_L2O16  ((size_t)18776064)     // f16
#define OFF_U2     ((size_t)20086784)     // 1280x512 f32
#define OFF_V2     ((size_t)22708224)     // 256x512 f32
#define OFF_CTX16  ((size_t)23232512)     // 256x512 f16
#define OFF_H3     ((size_t)23494656)     // 256x256 f32

DEV float sigf(float x) { return 1.f / (1.f + __expf(-x)); }
DEV float tanhfast(float x) { float e = __expf(2.f * x); return 1.f - 2.f / (e + 1.f); }
// permuted col c' -> original row g*512+h, g=(c'>>4)&3, h=(c'>>6)*16+(c'&15)
DEV int permrow(int c) { return (((c >> 4) & 3) << 9) | ((c >> 6) << 4) | (c & 15); }

DEV void gload16(const f16* g, f16x8* lds) {
  __builtin_amdgcn_global_load_lds((const __attribute__((address_space(1))) void*)g,
                                   (__attribute__((address_space(3))) void*)lds, 16, 0, 0);
}

// ---------------- 128x128 fp16 MFMA GEMM core (counted-vmcnt 2-barrier, 4 waves) ----------------
DEV void gemm_core(const f16* __restrict__ A, const f16* __restrict__ Bt, int K,
                   int rowBase, int colBase, f16x8* sh, f32x4 (&acc)[4][4]) {
  const int t = threadIdx.x, lane = t & 63, w = t >> 6;
  const int wr = (w >> 1) * 64, wc = (w & 1) * 64;
  const f16* Arow = A + (size_t)rowBase * K;
  const f16* Brow = Bt + (size_t)colBase * K;
  auto stage = [&](f16x8* dstBase, const f16* src, int k0) {
#pragma unroll
    for (int i = 0; i < 4; ++i) {
      int c = i * 256 + t; int r = c >> 3; int cc = (c & 7) ^ (r & 7);
      gload16(src + (size_t)r * K + (k0 + cc * 8), dstBase + i * 256 + (t & 192));
    }
  };
  stage(sh, Arow, 0);
  stage(sh + 2048, Brow, 0);
  const int nk = K >> 6;
  for (int kt = 0; kt < nk; ++kt) {
    const int cur = kt & 1;
    if (kt + 1 < nk) {
      stage(sh + (cur ^ 1) * 1024, Arow, (kt + 1) * 64);
      stage(sh + 2048 + (cur ^ 1) * 1024, Brow, (kt + 1) * 64);
      asm volatile("s_waitcnt vmcnt(8)" ::: "memory");
    } else {
      asm volatile("s_waitcnt vmcnt(0)" ::: "memory");
    }
    __builtin_amdgcn_s_barrier();
    __builtin_amdgcn_sched_barrier(0);
    const f16x8* shA = sh + cur * 1024;
    const f16x8* shB = sh + 2048 + cur * 1024;
    const int rr = lane & 15, chb = lane >> 4;
#pragma unroll
    for (int kk = 0; kk < 2; ++kk) {
      const int ch = kk * 4 + chb;
      f16x8 af[4], bf[4];
#pragma unroll
      for (int m = 0; m < 4; ++m) { int row = wr + m * 16 + rr; af[m] = shA[row * 8 + (ch ^ (row & 7))]; }
#pragma unroll
      for (int n = 0; n < 4; ++n) { int row = wc + n * 16 + rr; bf[n] = shB[row * 8 + (ch ^ (row & 7))]; }
#pragma unroll
      for (int m = 0; m < 4; ++m)
#pragma unroll
        for (int n = 0; n < 4; ++n)
          acc[m][n] = __builtin_amdgcn_mfma_f32_16x16x32_f16(af[m], bf[n], acc[m][n], 0, 0, 0);
    }
    __builtin_amdgcn_sched_barrier(0);
    __builtin_amdgcn_s_barrier();
  }
}

// ---------------- 256x256 fp16 MFMA GEMM core (8 waves; prologue + score) ----------------
DEV void gemm_core256(const f16* __restrict__ A, const f16* __restrict__ Bt, int K,
                      int rowBase, int colBase, f16x8 (&shA)[2][2048], f16x8 (&shB)[2][2048],
                      f32x4 (&acc)[8][4]) {
  const int t = threadIdx.x, lane = t & 63, w = t >> 6;
  const int wm = w >> 2, wn = w & 3;       // 2 x 4 wave grid; wave owns 128x64
  const f16* Arow = A + (size_t)rowBase * K;
  const f16* Brow = Bt + (size_t)colBase * K;
  auto stage = [&](f16x8* dst, const f16* src, int k0) {
#pragma unroll
    for (int i = 0; i < 4; ++i) {
      int c = i * 512 + t; int r = c >> 3; int cc = (c & 7) ^ (r & 7);
      gload16(src + (size_t)r * K + (k0 + cc * 8), dst + i * 512 + (t & 448));
    }
  };
  stage(shA[0], Arow, 0);
  stage(shB[0], Brow, 0);
  const int nk = K >> 6;
  for (int kt = 0; kt < nk; ++kt) {
    const int cur = kt & 1;
    if (kt + 1 < nk) {
      stage(shA[cur ^ 1], Arow, (kt + 1) * 64);
      stage(shB[cur ^ 1], Brow, (kt + 1) * 64);
      asm volatile("s_waitcnt vmcnt(8)" ::: "memory");
    } else {
      asm volatile("s_waitcnt vmcnt(0)" ::: "memory");
    }
    __builtin_amdgcn_s_barrier();
    __builtin_amdgcn_sched_barrier(0);
    const f16x8* pA = shA[cur];
    const f16x8* pB = shB[cur];
    const int rr = lane & 15, chb = lane >> 4;
#pragma unroll
    for (int kk = 0; kk < 2; ++kk) {
      const int ch = kk * 4 + chb;
      f16x8 bf[4];
#pragma unroll
      for (int n = 0; n < 4; ++n) { int row = wn * 64 + n * 16 + rr; bf[n] = pB[row * 8 + (ch ^ (row & 7))]; }
#pragma unroll
      for (int m = 0; m < 8; ++m) {
        int row = wm * 128 + m * 16 + rr;
        f16x8 af = pA[row * 8 + (ch ^ (row & 7))];
#pragma unroll
        for (int n = 0; n < 4; ++n)
          acc[m][n] = __builtin_amdgcn_mfma_f32_16x16x32_f16(af, bf[n], acc[m][n], 0, 0, 0);
      }
    }
    __builtin_amdgcn_sched_barrier(0);
    __builtin_amdgcn_s_barrier();
  }
}

// prologue ux GEMM (slabs 0,1): 256^2 tile, f16 out. grid (N/256, rows/256)
__global__ __launch_bounds__(512, 1) void k_gemm256(const f16* __restrict__ A, const f16* __restrict__ Bt,
                                                    int K, int N, f16* __restrict__ C16) {
  __shared__ f16x8 shA[2][2048];
  __shared__ f16x8 shB[2][2048];
  const int rb = blockIdx.y * 256, cb = blockIdx.x * 256;
  f32x4 acc[8][4] = {};
  gemm_core256(A, Bt, K, rb, cb, shA, shB, acc);
  const int t = threadIdx.x, lane = t & 63, w = t >> 6;
  const int wm = w >> 2, wn = w & 3;
  const int ec = lane & 15, er = (lane >> 4) * 4;
#pragma unroll
  for (int m = 0; m < 8; ++m)
#pragma unroll
    for (int n = 0; n < 4; ++n) {
      const int c = cb + wn * 64 + n * 16 + ec;
#pragma unroll
      for (int j = 0; j < 4; ++j) {
        const int r = rb + wm * 128 + m * 16 + er + j;
        C16[(size_t)r * N + c] = (f16)acc[m][n][j];
      }
    }
}

// attn1 score on the 256^2 core
__global__ __launch_bounds__(512, 1) void k_score2(const f16* __restrict__ outs, const f16* __restrict__ W2t,
    const float* __restrict__ W2b, const float* __restrict__ w1l, const float* __restrict__ V,
    float* __restrict__ score) {
  __shared__ f16x8 shA[2][2048];
  __shared__ f16x8 shB[2][2048];
  __shared__ float sacc[256];
  const int rb = blockIdx.y * 256, cb = blockIdx.x * 256;
  f32x4 acc[8][4] = {};
  gemm_core256(outs, W2t, 512, rb, cb, shA, shB, acc);
  const int t = threadIdx.x, lane = t & 63, w = t >> 6;
  const int wm = w >> 2, wn = w & 3;
  const int ec = lane & 15, er = (lane >> 4) * 4;
  if (t < 256) sacc[t] = 0.f;
  __syncthreads();
#pragma unroll
  for (int m = 0; m < 8; ++m)
#pragma unroll
    for (int j = 0; j < 4; ++j) {
      const int lr = wm * 128 + m * 16 + er + j;
      const int r = rb + lr;
      const int d = (r / 30) >> 8;
      float p = 0.f;
#pragma unroll
      for (int n = 0; n < 4; ++n) {
        const int c = cb + wn * 64 + n * 16 + ec;
        p += V[c] * tanhfast(acc[m][n][j] + W2b[c] + w1l[d * 512 + c]);
      }
      p += __shfl_xor(p, 1); p += __shfl_xor(p, 2); p += __shfl_xor(p, 4); p += __shfl_xor(p, 8);
      if (ec == 0) atomicAdd(&sacc[lr], p);
    }
  __syncthreads();
  if (t < 256) atomicAdd(&score[rb + t], sacc[t]);
}

// ---------------- generic bias/act GEMM wrapper (2D grid, 128^2) ----------------
template <int ACT, bool O32, bool O16>
__global__ __launch_bounds__(256, 2) void k_gemm(const f16* __restrict__ A, const f16* __restrict__ Bt,
                                                 int K, int N, const float* __restrict__ bias,
                                                 float* __restrict__ C32, f16* __restrict__ C16) {
  __shared__ f16x8 sh[4096];
  const int rb = blockIdx.y * 128, cb = blockIdx.x * 128;
  f32x4 acc[4][4] = {};
  gemm_core(A, Bt, K, rb, cb, sh, acc);
  const int t = threadIdx.x, lane = t & 63, w = t >> 6;
  const int wr = (w >> 1) * 64, wc = (w & 1) * 64, ec = lane & 15, er = (lane >> 4) * 4;
#pragma unroll
  for (int m = 0; m < 4; ++m)
#pragma unroll
    for (int n = 0; n < 4; ++n) {
      const int c = cb + wc + n * 16 + ec;
      const float bv = bias ? bias[c] : 0.f;
#pragma unroll
      for (int j = 0; j < 4; ++j) {
        const int r = rb + wr + m * 16 + er + j;
        float v = acc[m][n][j] + bv;
        if (ACT == 3) v = fmaxf(v, 0.f);
        if (O32) C32[(size_t)r * N + c] = v;
        if (O16) C16[(size_t)r * N + c] = (f16)v;
      }
    }
}

// ---------------- merged TimeLSTM step + ux co-GEMM ----------------
// Blocks 0..159: fused step s (R6/R10-verified math). Blocks 160..319 (s<=27): 128^2 ux tiles
// of slab s+2 on the 96 idle CUs. ux/x16 s-major; slab s+2 coherent via 2 kernel boundaries.
__global__ __launch_bounds__(256, 1) void k_stepm(
    const f16* __restrict__ hin, const f16* __restrict__ cin16, const float* __restrict__ cin32,
    const f16* __restrict__ Wallp, const f16* __restrict__ Wd16,
    const f16* __restrict__ ux, const float* __restrict__ ballp, const float* __restrict__ Wd_b,
    const float* __restrict__ tft,
    float* __restrict__ cout32, f16* __restrict__ cout16, f16* __restrict__ hout,
    f16* __restrict__ outs,
    const f16* __restrict__ x16s, const f16* __restrict__ U16p, f16* __restrict__ uxout, int s) {
  __shared__ f16x8 shAll[9728];   // 152 KB
  const int bid = (int)blockIdx.x;
  const int t = threadIdx.x, lane = t & 63, w = t >> 6;
  const int wr = (w >> 1) * 64, wc = (w & 1) * 64;
  const int ec = lane & 15, er = (lane >> 4) * 4;

  if (bid >= 160) {
    // ---- ux co-block: one 128^2 tile of slab s+2 ----
    const int q = bid - 160;
    const int slab = s + 2;
    const int rbu = (q >> 4) * 128, cbu = (q & 15) * 128;
    f32x4 acc[4][4] = {};
    gemm_core(x16s + (size_t)slab * 1280 * 768, U16p, 768, rbu, cbu, shAll, acc);
    f16* C = uxout + (size_t)slab * 1280 * 2048;
#pragma unroll
    for (int m = 0; m < 4; ++m)
#pragma unroll
      for (int n = 0; n < 4; ++n) {
        const int c = cbu + wc + n * 16 + ec;
#pragma unroll
        for (int j = 0; j < 4; ++j)
          C[(size_t)(rbu + wr + m * 16 + er + j) * 2048 + c] = (f16)acc[m][n][j];
      }
    return;
  }

  // ---- step path (R6/R10-verified) ----
  f16x8* shA = shAll;
  f16x8* shB = shAll + 2048;
  f16x8* shC = shAll + 4096;
  f16x8* shD = shAll + 6144;
  f16x8* shU = shAll + 6656;
  f16x8* shE = shAll + 8704;
  const int rb = (bid >> 4) * 128;
  const int cg = bid & 15;
  const int rr = lane & 15, chb = lane >> 4;
  const int h = cg * 32 + (w & 1) * 16 + ec;
  const int hcol = (w & 1) * 16 + ec;
  const f16* Ah = hin + (size_t)rb * 512;
  const f16* Ac = cin16 + (size_t)rb * 512;
  const f16* Bw = Wallp + (size_t)cg * 128 * 512;
  const f16* Bd = Wd16 + (size_t)cg * 32 * 512;
  const f16* uxs = ux + (size_t)s * 1280 * 2048;
  float bW[4];
#pragma unroll
  for (int n = 0; n < 4; ++n) bW[n] = ballp[cg * 128 + wc + n * 16 + ec];
  const float bD = Wd_b[h];
  const f16* shUf = (const f16*)shU;
  const float* shEf = (const float*)shE;
  const int kbase = (wc >> 3) + (ec >> 3);
  f32x4 acc[4][4] = {};
  f32x4 acc2[4] = {};

  auto stage128 = [&](f16x8* dstBase, const f16* src, int k0) {
#pragma unroll
    for (int i = 0; i < 4; ++i) {
      int c = i * 256 + t; int r = c >> 3; int cc = (c & 7) ^ (r & 7);
      gload16(src + (size_t)r * 512 + (k0 + cc * 8), dstBase + i * 256 + (t & 192));
    }
  };
  auto stage32 = [&](f16x8* dstBase, const f16* src, int k0) {
    const int r = t >> 3; const int cc = (t & 7) ^ (r & 7);
    gload16(src + (size_t)r * 512 + (k0 + cc * 8), dstBase + (t & 192));
  };
  auto stageU = [&]() {   // s-major slab: row (rb+lr), stride 2048
#pragma unroll
    for (int i = 0; i < 8; ++i) {
      int c = i * 256 + t; int lr = c >> 4; int k = c & 15;
      int klog = k ^ (((lr >> 2) & 3) << 1);
      gload16(uxs + (size_t)(rb + lr) * 2048 + cg * 128 + klog * 8, shU + i * 256 + (t & 192));
    }
  };
  auto stageE = [&]() {
#pragma unroll
    for (int i = 0; i < 4; ++i) {
      int c = i * 256 + t; int lr = c >> 3; int k = c & 7;
      int klog = k ^ (((lr >> 2) & 1) << 2);
      gload16((const f16*)(cin32 + (size_t)(rb + lr) * 512 + cg * 32 + klog * 4),
              shE + i * 256 + (t & 192));
    }
  };

  if (s == 0) {
    stageU();
    stageE();
    asm volatile("s_waitcnt vmcnt(0)" ::: "memory");
    __builtin_amdgcn_s_barrier();
  } else {
    stage128(shA, Ah, 0);
    stage128(shB, Bw, 0);
    stage128(shC, Ac, 0);
    stage32(shD, Bd, 0);
    stageU();
    stageE();
    for (int kt = 0; kt < 8; ++kt) {
      const int cur = kt & 1;
      if (kt < 7) {
        stage128(shA + (cur ^ 1) * 1024, Ah, (kt + 1) * 64);
        stage128(shB + (cur ^ 1) * 1024, Bw, (kt + 1) * 64);
        stage128(shC + (cur ^ 1) * 1024, Ac, (kt + 1) * 64);
        stage32(shD + (cur ^ 1) * 256, Bd, (kt + 1) * 64);
        asm volatile("s_waitcnt vmcnt(13)" ::: "memory");
      } else {
        asm volatile("s_waitcnt vmcnt(0)" ::: "memory");
      }
      __builtin_amdgcn_s_barrier();
      __builtin_amdgcn_sched_barrier(0);
      const f16x8* pA = shA + cur * 1024;
      const f16x8* pB = shB + cur * 1024;
      const f16x8* pC = shC + cur * 1024;
      const f16x8* pD = shD + cur * 256;
#pragma unroll
      for (int kk = 0; kk < 2; ++kk) {
        const int ch = kk * 4 + chb;
        f16x8 af[4], bf[4], cf[4], df;
#pragma unroll
        for (int m = 0; m < 4; ++m) {
          const int row = wr + m * 16 + rr;
          af[m] = pA[row * 8 + (ch ^ (row & 7))];
          cf[m] = pC[row * 8 + (ch ^ (row & 7))];
        }
#pragma unroll
        for (int n = 0; n < 4; ++n) { const int row = wc + n * 16 + rr; bf[n] = pB[row * 8 + (ch ^ (row & 7))]; }
        { const int row = (w & 1) * 16 + rr; df = pD[row * 8 + (ch ^ (row & 7))]; }
#pragma unroll
        for (int m = 0; m < 4; ++m) {
#pragma unroll
          for (int n = 0; n < 4; ++n)
            acc[m][n] = __builtin_amdgcn_mfma_f32_16x16x32_f16(af[m], bf[n], acc[m][n], 0, 0, 0);
          acc2[m] = __builtin_amdgcn_mfma_f32_16x16x32_f16(cf[m], df, acc2[m], 0, 0, 0);
        }
      }
      __builtin_amdgcn_sched_barrier(0);
      __builtin_amdgcn_s_barrier();
    }
  }

  // epilogue: full cell update; ux/c32 from swizzled LDS, tf from tft. (verified R5/R6/R10)
#pragma unroll
  for (int m = 0; m < 4; ++m)
#pragma unroll
    for (int j = 0; j < 4; ++j) {
      const int lr = wr + m * 16 + er + j;
      const int r = rb + lr;
      const float tv = tft[s * 1280 + r];
      const int sU = ((lr >> 2) & 3) << 1;
      const float u0 = (float)shUf[(lr * 16 + ((kbase + 0) ^ sU)) * 8 + (ec & 7)];
      const float u1 = (float)shUf[(lr * 16 + ((kbase + 2) ^ sU)) * 8 + (ec & 7)];
      const float u2v = (float)shUf[(lr * 16 + ((kbase + 4) ^ sU)) * 8 + (ec & 7)];
      const float u3 = (float)shUf[(lr * 16 + ((kbase + 6) ^ sU)) * 8 + (ec & 7)];
      const float p0 = acc[m][0][j] + bW[0] + u0;
      const float p1 = acc[m][1][j] + bW[1] + u1;
      const float p2 = acc[m][2][j] + bW[2] + u2v;
      const float p3 = acc[m][3][j] + bW[3] + u3;
      const float f = sigf(p0), i = sigf(p1), o = sigf(p2), ct = sigf(p3);
      const float cs = tanhfast(acc2[m][j] + bD);
      const int sE = ((lr >> 2) & 1) << 2;
      const float c_old = shEf[(lr * 8 + ((hcol >> 2) ^ sE)) * 4 + (hcol & 3)];
      const float cadj = c_old - cs + cs * tv;
      const float cn = f * cadj + i * ct;
      cout32[(size_t)r * 512 + h] = cn;
      cout16[(size_t)r * 512 + h] = (f16)cn;
      hout[(size_t)r * 512 + h] = (f16)(o * tanhfast(cn));
      outs[((size_t)r * 30 + s) * 512 + h] = (f16)o;
    }
}

// ---------------- fused lstm2 step ----------------
__global__ __launch_bounds__(256, 2) void k_l2step(const f16* __restrict__ hin, const f16* __restrict__ Whhp,
    const float* __restrict__ xi2, const float* __restrict__ cin, float* __restrict__ cout,
    f16* __restrict__ hout, float* __restrict__ l2o32, f16* __restrict__ l2o16, int ts) {
  __shared__ f16x8 sh[4096];
  const int rb = (blockIdx.x >> 4) * 128, cg = blockIdx.x & 15;
  f32x4 acc[4][4] = {};
  gemm_core(hin, Whhp, 512, rb, cg * 128, sh, acc);
  const int t = threadIdx.x, lane = t & 63, w = t >> 6;
  const int wr = (w >> 1) * 64, wc = (w & 1) * 64, ec = lane & 15, er = (lane >> 4) * 4;
  const int h = cg * 32 + (w & 1) * 16 + ec;
#pragma unroll
  for (int m = 0; m < 4; ++m)
#pragma unroll
    for (int j = 0; j < 4; ++j) {
      const int r = rb + wr + m * 16 + er + j;
      const size_t xb = ((size_t)r * 5 + ts) * 2048 + cg * 128 + wc + ec;
      const float p0 = acc[m][0][j] + xi2[xb];
      const float p1 = acc[m][1][j] + xi2[xb + 16];
      const float p2 = acc[m][2][j] + xi2[xb + 32];
      const float p3 = acc[m][3][j] + xi2[xb + 48];
      const float ii = sigf(p0), ff = sigf(p1), gg = tanhfast(p2), oo = sigf(p3);
      const float cn = ff * cin[(size_t)r * 512 + h] + ii * gg;
      const float hn = oo * tanhfast(cn);
      cout[(size_t)r * 512 + h] = cn;
      hout[(size_t)r * 512 + h] = (f16)hn;
      const size_t ob = ((size_t)r * 5 + ts) * 512 + h;
      l2o32[ob] = hn;
      l2o16[ob] = (f16)hn;
    }
}

// w1last[d] = A1_W1 @ outs[d, B-1, len-1] + b
__global__ __launch_bounds__(256) void k_w1last(const f16* __restrict__ outs, const int* __restrict__ lens,
                                                const float* __restrict__ W1, const float* __restrict__ W1b,
                                                float* __restrict__ w1l) {
  __shared__ float lastv[512];
  const int d = blockIdx.x;
  const int idx = lens[255 * 5 + d] - 1;
  const size_t row = ((size_t)(d * 256 + 255) * 30 + idx) * 512;
  for (int h = threadIdx.x; h < 512; h += 256) lastv[h] = (float)outs[row + h];
  __syncthreads();
  for (int h = threadIdx.x; h < 512; h += 256) {
    const float* wr = W1 + (size_t)h * 512;
    float p = W1b[h];
    for (int k = 0; k < 512; ++k) p += lastv[k] * wr[k];
    w1l[d * 512 + h] = p;
  }
}

// attn1 softmax + weighted sum
__global__ __launch_bounds__(256) void k_attn1(const float* __restrict__ score, const f16* __restrict__ outs,
                                               const int* __restrict__ lens,
                                               float* __restrict__ l1o32, f16* __restrict__ l1o16) {
  __shared__ float saw[32];
  const int n = blockIdx.x;
  const int d = n >> 8, b = n & 255;
  const int len = lens[b * 5 + d];
  const int t = threadIdx.x, lane = t & 63, w = t >> 6;
  if (w == 0) {
    const bool valid = lane < len;
    float sc = valid ? score[(size_t)n * 30 + lane] : -INFINITY;
    float mx = sc;
#pragma unroll
    for (int off = 32; off > 0; off >>= 1) mx = fmaxf(mx, __shfl_xor(mx, off));
    float e = valid ? __expf(sc - mx) : 0.f;
    float sm = e;
#pragma unroll
    for (int off = 32; off > 0; off >>= 1) sm += __shfl_xor(sm, off);
    if (lane < 30) saw[lane] = e / sm;
  }
  __syncthreads();
  for (int h = t; h < 512; h += 256) {
    float acc = 0.f;
    for (int s = 0; s < len; ++s) acc += saw[s] * (float)outs[((size_t)n * 30 + s) * 512 + h];
    const size_t o = ((size_t)b * 5 + d) * 512 + h;
    l1o32[o] = acc;
    l1o16[o] = (f16)acc;
  }
}

// merged u2/v2 GEMMs for attn2
__global__ __launch_bounds__(256, 2) void k_uv(const f16* __restrict__ l2o16, const f16* __restrict__ A2W2c,
    const f16* __restrict__ h2fin, const f16* __restrict__ A2W1c,
    const float* __restrict__ bu, const float* __restrict__ bv,
    float* __restrict__ u2, float* __restrict__ v2) {
  __shared__ f16x8 sh[4096];
  const int bid = blockIdx.x;
  const f16* A; const f16* B; const float* bias; float* out; int rb, cb;
  if (bid < 40) { A = l2o16; B = A2W2c; bias = bu; out = u2; rb = (bid >> 2) * 128; cb = (bid & 3) * 128; }
  else { int b2 = bid - 40; A = h2fin; B = A2W1c; bias = bv; out = v2; rb = (b2 >> 2) * 128; cb = (b2 & 3) * 128; }
  f32x4 acc[4][4] = {};
  gemm_core(A, B, 512, rb, cb, sh, acc);
  const int t = threadIdx.x, lane = t & 63, w = t >> 6;
  const int wr = (w >> 1) * 64, wc = (w & 1) * 64, ec = lane & 15, er = (lane >> 4) * 4;
#pragma unroll
  for (int m = 0; m < 4; ++m)
#pragma unroll
    for (int n = 0; n < 4; ++n) {
      const int c = cb + wc + n * 16 + ec;
      const float bvv = bias[c];
#pragma unroll
      for (int j = 0; j < 4; ++j) out[(size_t)(rb + wr + m * 16 + er + j) * 512 + c] = acc[m][n][j] + bvv;
    }
}

// attn2 over D=5 days
__global__ __launch_bounds__(256) void k_attn2(const float* __restrict__ u2, const float* __restrict__ v2,
                                               const float* __restrict__ l2o, const float* __restrict__ V2,
                                               const float* __restrict__ V2b, f16* __restrict__ ctx16) {
  __shared__ float ssc[8];
  __shared__ float saw[8];
  const int b = blockIdx.x;
  const int t = threadIdx.x, lane = t & 63, w = t >> 6;
  for (int tt = w; tt < 5; tt += 4) {
    const float* ur = u2 + ((size_t)b * 5 + tt) * 512;
    const float* vr = v2 + (size_t)b * 512;
    float p = 0.f;
#pragma unroll
    for (int j = 0; j < 8; ++j) { int h = lane * 8 + j; p += V2[h] * tanhfast(ur[h] + vr[h]); }
#pragma unroll
    for (int off = 32; off > 0; off >>= 1) p += __shfl_down(p, off);
    if (lane == 0) ssc[tt] = p + V2b[0];
  }
  __syncthreads();
  if (w == 0) {
    const bool valid = lane < 5;
    float sc = valid ? ssc[lane] : -INFINITY;
    float mx = sc;
#pragma unroll
    for (int off = 32; off > 0; off >>= 1) mx = fmaxf(mx, __shfl_xor(mx, off));
    float e = valid ? __expf(sc - mx) : 0.f;
    float sm = e;
#pragma unroll
    for (int off = 32; off > 0; off >>= 1) sm += __shfl_xor(sm, off);
    if (valid) saw[lane] = e / sm;
  }
  __syncthreads();
  for (int h = t; h < 512; h += 256) {
    float a = 0.f;
#pragma unroll
    for (int tt = 0; tt < 5; ++tt) a += saw[tt] * l2o[((size_t)b * 5 + tt) * 512 + h];
    ctx16[(size_t)b * 512 + h] = (f16)a;
  }
}

// final: out = h3 @ lin4^T + b4
__global__ __launch_bounds__(256) void k_final(const float* __restrict__ h3, const float* __restrict__ W4,
                                               const float* __restrict__ b4, float* __restrict__ out) {
  const int idx = blockIdx.x * 256 + threadIdx.x;
  const int b = idx >> 1, o = idx & 1;
  const float* hr = h3 + b * 256;
  const float* wr = W4 + o * 256;
  float p = b4[o];
  for (int j = 0; j < 256; ++j) p += hr[j] * wr[j];
  out[idx] = p;
}

// ---------------- prep kernels ----------------
// cast sentence_feats to s-major x16s[s][n][768], n = d*256+b
__global__ __launch_bounds__(256) void k_castx(const float* __restrict__ sf, f16* __restrict__ x16s) {
  const int total = 7372800;  // 38400*768/4
  for (int e = blockIdx.x * 256 + threadIdx.x; e < total; e += gridDim.x * 256) {
    const int row = e / 192, k = e - row * 192;
    const int b = row / 150, rem = row - b * 150;
    const int d = rem / 30, s = rem - d * 30;
    const int orow = s * 1280 + d * 256 + b;
    const float4 v = ((const float4*)sf)[e];
    f16x4 o = {(f16)v.x, (f16)v.y, (f16)v.z, (f16)v.w};
    ((f16x4*)x16s)[(size_t)orow * 192 + k] = o;
  }
}

// merged weight cast (+optional gate permutation)
struct WPArgs { const float* src[9]; f16* dst[9]; int k4[9]; int cnt4[9]; int perm[9]; };
__global__ __launch_bounds__(256) void k_castwp(WPArgs a) {
  int g = blockIdx.x * 256 + threadIdx.x;
#pragma unroll
  for (int si = 0; si < 9; ++si) {
    if (g < a.cnt4[si]) {
      const int K4 = a.k4[si];
      const int c = g / K4, k = g - c * K4;
      const int srow = a.perm[si] ? permrow(c) : c;
      const float4 v = ((const float4*)a.src[si])[(size_t)srow * K4 + k];
      f16x4 o = {(f16)v.x, (f16)v.y, (f16)v.z, (f16)v.w};
      ((f16x4*)a.dst[si])[(size_t)c * K4 + k] = o;
      return;
    }
    g -= a.cnt4[si];
  }
}

// state init + tft + score. PERSISTENT/FRESH regions ONLY — must NOT touch the x16s overlay
// (R8/R9 bug: zeroing h2/c2 here clobbered live x16s rows 9493-10352).
__global__ __launch_bounds__(256) void k_zero(f16* h16a, f16* c16a, float* c32a,
    float* ballp, float* bihp, const float* Wall_b, const float* Uall_b,
    const float* bih, const float* bhh, float* tft, const float* tf,
    float* score, const float* Vb) {
  const int i = blockIdx.x * 256 + threadIdx.x;
  if (i < 655360) { h16a[i] = (f16)0.f; c16a[i] = (f16)0.f; c32a[i] = 0.f; }
  if (i < 2048) {
    const int p = permrow(i);
    ballp[i] = Wall_b[p] + Uall_b[p];
    bihp[i] = bih[p] + bhh[p];
  }
  if (i < 38400) {
    const int s = i / 1280, r = i - s * 1280;
    const int d = r >> 8, b = r & 255;
    tft[i] = tf[((size_t)b * 5 + d) * 30 + s];
    score[i] = Vb[0];
  }
}

// lstm2 state init — runs AFTER the recurrence (x16s dead), h2/c2 live in the overlay region
__global__ __launch_bounds__(256) void k_init2(f16* h2a, float* c2a) {
  const int i = blockIdx.x * 256 + threadIdx.x;
  if (i < 131072) { h2a[i] = (f16)0.f; c2a[i] = 0.f; }
}

// ---------------- launch ----------------
extern "C" void kernel_launch(void* const* d_in, const int* in_sizes, int n_in,
                              void* d_out, int out_size, void* d_ws, size_t ws_size,
                              hipStream_t stream) {
  const float* sf     = (const float*)d_in[0];
  const float* tf     = (const float*)d_in[1];
  const int*   lens   = (const int*)d_in[2];
  const float* Wd_w   = (const float*)d_in[3];
  const float* Wd_b   = (const float*)d_in[4];
  const float* Wall_w = (const float*)d_in[5];
  const float* Wall_b = (const float*)d_in[6];
  const float* Uall_w = (const float*)d_in[7];
  const float* Uall_b = (const float*)d_in[8];
  const float* A1W1   = (const float*)d_in[9];
  const float* A1W1b  = (const float*)d_in[10];
  const float* A1W2   = (const float*)d_in[11];
  const float* A1W2b  = (const float*)d_in[12];
  const float* A1V    = (const float*)d_in[13];
  const float* A1Vb   = (const float*)d_in[14];
  const float* Wih    = (const float*)d_in[15];
  const float* Whh    = (const float*)d_in[16];
  const float* bih    = (const float*)d_in[17];
  const float* bhh    = (const float*)d_in[18];
  const float* A2W1   = (const float*)d_in[19];
  const float* A2W1b  = (const float*)d_in[20];
  const float* A2W2   = (const float*)d_in[21];
  const float* A2W2b  = (const float*)d_in[22];
  const float* A2V    = (const float*)d_in[23];
  const float* A2Vb   = (const float*)d_in[24];
  const float* L3w    = (const float*)d_in[25];
  const float* L3b    = (const float*)d_in[26];
  const float* L4w    = (const float*)d_in[27];
  const float* L4b    = (const float*)d_in[28];

  if (ws_size < WS_NEED) return;
  char* ws = (char*)d_ws;
  f16*   x16s   = (f16*)(ws + OFF_X16);
  f16*   ux16   = (f16*)(ws + OFF_UX);
  f16*   outs16 = (f16*)(ws + OFF_OUTS);
  f16*   Wd16   = (f16*)(ws + OFF_WD);
  f16*   Wallp  = (f16*)(ws + OFF_WALLP);
  f16*   U16p   = (f16*)(ws + OFF_UP);
  f16*   W216   = (f16*)(ws + OFF_W2);
  f16*   Wihp   = (f16*)(ws + OFF_WIHP);
  f16*   Whhp   = (f16*)(ws + OFF_WHHP);
  f16*   A2W116 = (f16*)(ws + OFF_A2W1C);
  f16*   A2W216 = (f16*)(ws + OFF_A2W2C);
  f16*   L316   = (f16*)(ws + OFF_L3WC);
  float* ballp  = (float*)(ws + OFF_BALLP);
  float* bihp   = (float*)(ws + OFF_BIHP);
  f16*   h16b[2]  = {(f16*)(ws + OFF_H16), (f16*)(ws + OFF_H16 + 1310720)};
  f16*   c16b[2]  = {(f16*)(ws + OFF_C16), (f16*)(ws + OFF_C16 + 1310720)};
  float* c32b[2]  = {(float*)(ws + OFF_C32), (float*)(ws + OFF_C32 + 2621440)};
  float* tft    = (float*)(ws + OFF_TFTN);
  float* score  = (float*)(ws + OFF_SCOREN);
  float* w1l    = (float*)(ws + OFF_W1L);
  float* l1o32  = (float*)(ws + OFF_L1O32);
  f16*   l1o16  = (f16*)(ws + OFF_L1O16);
  float* xi2    = (float*)(ws + OFF_XI2);
  float* c2b[2] = {(float*)(ws + OFF_C2), (float*)(ws + OFF_C2 + 524288)};
  f16*   h2b[2] = {(f16*)(ws + OFF_H2), (f16*)(ws + OFF_H2 + 262144)};
  float* l2o32  = (float*)(ws + OFF_L2O32);
  f16*   l2o16  = (f16*)(ws + OFF_L2O16);
  float* u2     = (float*)(ws + OFF_U2);
  float* v2     = (float*)(ws + OFF_V2);
  f16*   ctx16  = (f16*)(ws + OFF_CTX16);
  float* h3     = (float*)(ws + OFF_H3);

  // 1. input casts + init (k_zero touches ONLY persistent/fresh regions — x16s stays intact)
  k_castx<<<2048, 256, 0, stream>>>(sf, x16s);
  WPArgs wa;
  wa.src[0] = Wd_w;   wa.dst[0] = Wd16;   wa.k4[0] = 128; wa.cnt4[0] = 65536;  wa.perm[0] = 0;
  wa.src[1] = A1W2;   wa.dst[1] = W216;   wa.k4[1] = 128; wa.cnt4[1] = 65536;  wa.perm[1] = 0;
  wa.src[2] = A2W1;   wa.dst[2] = A2W116; wa.k4[2] = 128; wa.cnt4[2] = 65536;  wa.perm[2] = 0;
  wa.src[3] = A2W2;   wa.dst[3] = A2W216; wa.k4[3] = 128; wa.cnt4[3] = 65536;  wa.perm[3] = 0;
  wa.src[4] = L3w;    wa.dst[4] = L316;   wa.k4[4] = 128; wa.cnt4[4] = 32768;  wa.perm[4] = 0;
  wa.src[5] = Wall_w; wa.dst[5] = Wallp;  wa.k4[5] = 128; wa.cnt4[5] = 262144; wa.perm[5] = 1;
  wa.src[6] = Uall_w; wa.dst[6] = U16p;   wa.k4[6] = 192; wa.cnt4[6] = 393216; wa.perm[6] = 1;
  wa.src[7] = Wih;    wa.dst[7] = Wihp;   wa.k4[7] = 128; wa.cnt4[7] = 262144; wa.perm[7] = 1;
  wa.src[8] = Whh;    wa.dst[8] = Whhp;   wa.k4[8] = 128; wa.cnt4[8] = 262144; wa.perm[8] = 1;
  k_castwp<<<5760, 256, 0, stream>>>(wa);
  k_zero<<<2560, 256, 0, stream>>>(h16b[0], c16b[0], c32b[0], ballp, bihp, Wall_b, Uall_b, bih, bhh,
                                   tft, tf, score, A1Vb);

  // 2. ux prologue: slabs 0,1 (rows 0..2559 of s-major layout), 256^2 tiles
  k_gemm256<<<dim3(8, 10), 512, 0, stream>>>(x16s, U16p, 768, 2048, ux16);

  // 3. TimeLSTM recurrence: 30 launches; each carries the ux GEMM for slab s+2
  //    on the 96 CUs the 160-block step grid leaves idle.
  for (int s = 0; s < 30; ++s) {
    const int pi = s & 1, po = pi ^ 1;
    const int nb = (s <= 27) ? 320 : 160;
    k_stepm<<<nb, 256, 0, stream>>>(h16b[pi], c16b[pi], c32b[pi], Wallp, Wd16, ux16, ballp, Wd_b, tft,
                                    c32b[po], c16b[po], h16b[po], outs16,
                                    x16s, U16p, ux16, s);
  }

  // 4. lstm2 state init (x16s now dead; h2/c2 live in the overlay region)
  k_init2<<<512, 256, 0, stream>>>(h2b[0], c2b[0]);

  // 5. attn1
  k_w1last<<<5, 256, 0, stream>>>(outs16, lens, A1W1, A1W1b, w1l);
  k_score2<<<dim3(2, 150), 512, 0, stream>>>(outs16, W216, A1W2b, w1l, A1V, score);
  k_attn1<<<1280, 256, 0, stream>>>(score, outs16, lens, l1o32, l1o16);

  // 6. lstm2: xi2 (permuted cols, biases folded), then 5 fused steps
  k_gemm<0, true, false><<<dim3(16, 10), 256, 0, stream>>>(l1o16, Wihp, 512, 2048, bihp, xi2, nullptr);
  for (int ts = 0; ts < 5; ++ts) {
    const int pi = ts & 1, po = pi ^ 1;
    k_l2step<<<32, 256, 0, stream>>>(h2b[pi], Whhp, xi2, c2b[pi], c2b[po], h2b[po], l2o32, l2o16, ts);
  }

  // 7. attn2 (h2 final is buffer 1 after 5 steps)
  k_uv<<<48, 256, 0, stream>>>(l2o16, A2W216, h2b[1], A2W116, A2W2b, A2W1b, u2, v2);
  k_attn2<<<256, 256, 0, stream>>>(u2, v2, l2o32, A2V, A2Vb, ctx16);

  // 8. head
  k_gemm<3, true, false><<<dim3(2, 2), 256, 0, stream>>>(ctx16, L316, 512, 256, L3b, h3, nullptr);
  k_final<<<2, 256, 0, stream>>>(h3, L4w, L4b, (float*)d_out);
}

// Round 12
// 925.699 us; speedup vs baseline: 1.1005x; 1.0229x over previous
//
#include <hip/hip_runtime.h>
#include <math.h>

typedef _Float16 f16;
typedef _Float16 f16x4 __attribute__((ext_vector_type(4)));
typedef _Float16 f16x8 __attribute__((ext_vector_type(8)));
typedef float f32x4 __attribute__((ext_vector_type(4)));

#define DEV static __device__ __forceinline__

// ---------------- workspace layout (byte offsets; all 256-aligned) ----------------
// persistent region
#define OFF_X16    ((size_t)0)            // x16s [s][n][768] f16 (live until launch 27; tail overlays after)
#define OFF_UX     ((size_t)58982400)     // ux16 [s][n][2048] f16 s-major (permuted cols)
#define OFF_OUTS   ((size_t)216268800)    // outs16 38400x512 f16 (n*30+s row layout)
#define OFF_WD     ((size_t)255590400)    // Wd16 512x512
#define OFF_WALLP  ((size_t)256114688)    // Wall16 permuted 2048x512
#define OFF_UP     ((size_t)258211840)    // Uall16 permuted 2048x768
#define OFF_W2     ((size_t)261357568)    // A1_W2 512x512
#define OFF_WIHP   ((size_t)261881856)    // Wih16 permuted 2048x512
#define OFF_WHHP   ((size_t)263979008)    // Whh16 permuted 2048x512
#define OFF_A2W1C  ((size_t)266076160)    // A2_W1 512x512
#define OFF_A2W2C  ((size_t)266600448)    // A2_W2 512x512
#define OFF_L3WC   ((size_t)267124736)    // lin3 256x512
#define OFF_BALLP  ((size_t)267386880)    // permuted Wall_b+Uall_b 2048 f32
#define OFF_BIHP   ((size_t)267395072)    // permuted bih+bhh 2048 f32
#define OFF_H16    ((size_t)267403264)    // h16 ping-pong 2x 1280x512 f16
#define OFF_C16    ((size_t)270024704)    // c16 ping-pong
#define OFF_C32    ((size_t)272646144)    // c32 ping-pong 2x 1280x512 f32
#define OFF_TFTN   ((size_t)277889024)    // tft[s][r] 30x1280 f32 (fresh region)
#define OFF_SCOREN (OFF_TFTN + 153600)    // score 38400 f32 (fresh region)
#define WS_NEED    (OFF_SCOREN + 153600)
// tail region overlays X16 (x16s dead after launch 27; ALL writes below happen after the recurrence)
#define OFF_W1L    ((size_t)153600)       // 5x512 f32
#define OFF_L1O32  ((size_t)163840)       // 1280x512 f32
#define OFF_L1O16  ((size_t)2785280)      // 1280x512 f16
#define OFF_XI2    ((size_t)4096000)      // 1280x2048 f32 (permuted cols, biases included)
#define OFF_C2     ((size_t)14581760)     // ping-pong 2x 256x512 f32   (init by k_init2 AFTER recurrence)
#define OFF_H2     ((size_t)15630336)     // ping-pong 2x 256x512 f16   (init by k_init2 AFTER recurrence)
#define OFF_L2O32  ((size_t)16154624)     // 1280x512 f32
#define OFF_L2O16  ((size_t)18776064)     // f16
#define OFF_U2     ((size_t)20086784)     // 1280x512 f32
#define OFF_V2     ((size_t)22708224)     // 256x512 f32
#define OFF_CTX16  ((size_t)23232512)     // 256x512 f16
#define OFF_H3     ((size_t)23494656)     // 256x256 f32

DEV float sigf(float x) { return 1.f / (1.f + __expf(-x)); }
DEV float tanhfast(float x) { float e = __expf(2.f * x); return 1.f - 2.f / (e + 1.f); }
// permuted col c' -> original row g*512+h, g=(c'>>4)&3, h=(c'>>6)*16+(c'&15)
DEV int permrow(int c) { return (((c >> 4) & 3) << 9) | ((c >> 6) << 4) | (c & 15); }

DEV void gload16(const f16* g, f16x8* lds) {
  __builtin_amdgcn_global_load_lds((const __attribute__((address_space(1))) void*)g,
                                   (__attribute__((address_space(3))) void*)lds, 16, 0, 0);
}

// ---------------- 128x128 fp16 MFMA GEMM core (counted-vmcnt 2-barrier, 4 waves) ----------------
DEV void gemm_core(const f16* __restrict__ A, const f16* __restrict__ Bt, int K,
                   int rowBase, int colBase, f16x8* sh, f32x4 (&acc)[4][4]) {
  const int t = threadIdx.x, lane = t & 63, w = t >> 6;
  const int wr = (w >> 1) * 64, wc = (w & 1) * 64;
  const f16* Arow = A + (size_t)rowBase * K;
  const f16* Brow = Bt + (size_t)colBase * K;
  auto stage = [&](f16x8* dstBase, const f16* src, int k0) {
#pragma unroll
    for (int i = 0; i < 4; ++i) {
      int c = i * 256 + t; int r = c >> 3; int cc = (c & 7) ^ (r & 7);
      gload16(src + (size_t)r * K + (k0 + cc * 8), dstBase + i * 256 + (t & 192));
    }
  };
  stage(sh, Arow, 0);
  stage(sh + 2048, Brow, 0);
  const int nk = K >> 6;
  for (int kt = 0; kt < nk; ++kt) {
    const int cur = kt & 1;
    if (kt + 1 < nk) {
      stage(sh + (cur ^ 1) * 1024, Arow, (kt + 1) * 64);
      stage(sh + 2048 + (cur ^ 1) * 1024, Brow, (kt + 1) * 64);
      asm volatile("s_waitcnt vmcnt(8)" ::: "memory");
    } else {
      asm volatile("s_waitcnt vmcnt(0)" ::: "memory");
    }
    __builtin_amdgcn_s_barrier();
    __builtin_amdgcn_sched_barrier(0);
    const f16x8* shA = sh + cur * 1024;
    const f16x8* shB = sh + 2048 + cur * 1024;
    const int rr = lane & 15, chb = lane >> 4;
#pragma unroll
    for (int kk = 0; kk < 2; ++kk) {
      const int ch = kk * 4 + chb;
      f16x8 af[4], bf[4];
#pragma unroll
      for (int m = 0; m < 4; ++m) { int row = wr + m * 16 + rr; af[m] = shA[row * 8 + (ch ^ (row & 7))]; }
#pragma unroll
      for (int n = 0; n < 4; ++n) { int row = wc + n * 16 + rr; bf[n] = shB[row * 8 + (ch ^ (row & 7))]; }
#pragma unroll
      for (int m = 0; m < 4; ++m)
#pragma unroll
        for (int n = 0; n < 4; ++n)
          acc[m][n] = __builtin_amdgcn_mfma_f32_16x16x32_f16(af[m], bf[n], acc[m][n], 0, 0, 0);
    }
    __builtin_amdgcn_sched_barrier(0);
    __builtin_amdgcn_s_barrier();
  }
}

// ---------------- 256x256 fp16 MFMA GEMM core (8 waves; prologue only) ----------------
DEV void gemm_core256(const f16* __restrict__ A, const f16* __restrict__ Bt, int K,
                      int rowBase, int colBase, f16x8 (&shA)[2][2048], f16x8 (&shB)[2][2048],
                      f32x4 (&acc)[8][4]) {
  const int t = threadIdx.x, lane = t & 63, w = t >> 6;
  const int wm = w >> 2, wn = w & 3;       // 2 x 4 wave grid; wave owns 128x64
  const f16* Arow = A + (size_t)rowBase * K;
  const f16* Brow = Bt + (size_t)colBase * K;
  auto stage = [&](f16x8* dst, const f16* src, int k0) {
#pragma unroll
    for (int i = 0; i < 4; ++i) {
      int c = i * 512 + t; int r = c >> 3; int cc = (c & 7) ^ (r & 7);
      gload16(src + (size_t)r * K + (k0 + cc * 8), dst + i * 512 + (t & 448));
    }
  };
  stage(shA[0], Arow, 0);
  stage(shB[0], Brow, 0);
  const int nk = K >> 6;
  for (int kt = 0; kt < nk; ++kt) {
    const int cur = kt & 1;
    if (kt + 1 < nk) {
      stage(shA[cur ^ 1], Arow, (kt + 1) * 64);
      stage(shB[cur ^ 1], Brow, (kt + 1) * 64);
      asm volatile("s_waitcnt vmcnt(8)" ::: "memory");
    } else {
      asm volatile("s_waitcnt vmcnt(0)" ::: "memory");
    }
    __builtin_amdgcn_s_barrier();
    __builtin_amdgcn_sched_barrier(0);
    const f16x8* pA = shA[cur];
    const f16x8* pB = shB[cur];
    const int rr = lane & 15, chb = lane >> 4;
#pragma unroll
    for (int kk = 0; kk < 2; ++kk) {
      const int ch = kk * 4 + chb;
      f16x8 bf[4];
#pragma unroll
      for (int n = 0; n < 4; ++n) { int row = wn * 64 + n * 16 + rr; bf[n] = pB[row * 8 + (ch ^ (row & 7))]; }
#pragma unroll
      for (int m = 0; m < 8; ++m) {
        int row = wm * 128 + m * 16 + rr;
        f16x8 af = pA[row * 8 + (ch ^ (row & 7))];
#pragma unroll
        for (int n = 0; n < 4; ++n)
          acc[m][n] = __builtin_amdgcn_mfma_f32_16x16x32_f16(af, bf[n], acc[m][n], 0, 0, 0);
      }
    }
    __builtin_amdgcn_sched_barrier(0);
    __builtin_amdgcn_s_barrier();
  }
}

// prologue ux GEMM (slabs 0,1): 256^2 tile, f16 out. grid (N/256, rows/256)
__global__ __launch_bounds__(512, 1) void k_gemm256(const f16* __restrict__ A, const f16* __restrict__ Bt,
                                                    int K, int N, f16* __restrict__ C16) {
  __shared__ f16x8 shA[2][2048];
  __shared__ f16x8 shB[2][2048];
  const int rb = blockIdx.y * 256, cb = blockIdx.x * 256;
  f32x4 acc[8][4] = {};
  gemm_core256(A, Bt, K, rb, cb, shA, shB, acc);
  const int t = threadIdx.x, lane = t & 63, w = t >> 6;
  const int wm = w >> 2, wn = w & 3;
  const int ec = lane & 15, er = (lane >> 4) * 4;
#pragma unroll
  for (int m = 0; m < 8; ++m)
#pragma unroll
    for (int n = 0; n < 4; ++n) {
      const int c = cb + wn * 64 + n * 16 + ec;
#pragma unroll
      for (int j = 0; j < 4; ++j) {
        const int r = rb + wm * 128 + m * 16 + er + j;
        C16[(size_t)r * N + c] = (f16)acc[m][n][j];
      }
    }
}

// attn1 score fused into the 128^2 GEMM epilogue (R3-R6 verified):
// score[r] += sum_c V[c] * tanh(gemm + W2b[c] + w1l[d][c]);  score pre-initialized to Vb.
__global__ __launch_bounds__(256, 2) void k_score(const f16* __restrict__ outs, const f16* __restrict__ W2t,
    const float* __restrict__ W2b, const float* __restrict__ w1l, const float* __restrict__ V,
    float* __restrict__ score) {
  __shared__ f16x8 sh[4096];
  const int rb = blockIdx.y * 128, cb = blockIdx.x * 128;
  f32x4 acc[4][4] = {};
  gemm_core(outs, W2t, 512, rb, cb, sh, acc);
  const int t = threadIdx.x, lane = t & 63, w = t >> 6;
  const int wr = (w >> 1) * 64, wc = (w & 1) * 64, ec = lane & 15, er = (lane >> 4) * 4;
  float* sacc = (float*)sh;  // reuse LDS (gemm_core ends with a barrier)
  if (t < 128) sacc[t] = 0.f;
  __syncthreads();
#pragma unroll
  for (int m = 0; m < 4; ++m)
#pragma unroll
    for (int j = 0; j < 4; ++j) {
      const int lr = wr + m * 16 + er + j;
      const int r = rb + lr;
      const int d = (r / 30) >> 8;
      float p = 0.f;
#pragma unroll
      for (int n = 0; n < 4; ++n) {
        const int c = cb + wc + n * 16 + ec;
        p += V[c] * tanhfast(acc[m][n][j] + W2b[c] + w1l[d * 512 + c]);
      }
      p += __shfl_xor(p, 1); p += __shfl_xor(p, 2); p += __shfl_xor(p, 4); p += __shfl_xor(p, 8);
      if (ec == 0) atomicAdd(&sacc[lr], p);
    }
  __syncthreads();
  if (t < 128) atomicAdd(&score[rb + t], sacc[t]);
}

// ---------------- generic bias/act GEMM wrapper (2D grid, 128^2) ----------------
template <int ACT, bool O32, bool O16>
__global__ __launch_bounds__(256, 2) void k_gemm(const f16* __restrict__ A, const f16* __restrict__ Bt,
                                                 int K, int N, const float* __restrict__ bias,
                                                 float* __restrict__ C32, f16* __restrict__ C16) {
  __shared__ f16x8 sh[4096];
  const int rb = blockIdx.y * 128, cb = blockIdx.x * 128;
  f32x4 acc[4][4] = {};
  gemm_core(A, Bt, K, rb, cb, sh, acc);
  const int t = threadIdx.x, lane = t & 63, w = t >> 6;
  const int wr = (w >> 1) * 64, wc = (w & 1) * 64, ec = lane & 15, er = (lane >> 4) * 4;
#pragma unroll
  for (int m = 0; m < 4; ++m)
#pragma unroll
    for (int n = 0; n < 4; ++n) {
      const int c = cb + wc + n * 16 + ec;
      const float bv = bias ? bias[c] : 0.f;
#pragma unroll
      for (int j = 0; j < 4; ++j) {
        const int r = rb + wr + m * 16 + er + j;
        float v = acc[m][n][j] + bv;
        if (ACT == 3) v = fmaxf(v, 0.f);
        if (O32) C32[(size_t)r * N + c] = v;
        if (O16) C16[(size_t)r * N + c] = (f16)v;
      }
    }
}

// ---------------- merged TimeLSTM step + ux co-GEMM (R11-verified) ----------------
__global__ __launch_bounds__(256, 1) void k_stepm(
    const f16* __restrict__ hin, const f16* __restrict__ cin16, const float* __restrict__ cin32,
    const f16* __restrict__ Wallp, const f16* __restrict__ Wd16,
    const f16* __restrict__ ux, const float* __restrict__ ballp, const float* __restrict__ Wd_b,
    const float* __restrict__ tft,
    float* __restrict__ cout32, f16* __restrict__ cout16, f16* __restrict__ hout,
    f16* __restrict__ outs,
    const f16* __restrict__ x16s, const f16* __restrict__ U16p, f16* __restrict__ uxout, int s) {
  __shared__ f16x8 shAll[9728];   // 152 KB
  const int bid = (int)blockIdx.x;
  const int t = threadIdx.x, lane = t & 63, w = t >> 6;
  const int wr = (w >> 1) * 64, wc = (w & 1) * 64;
  const int ec = lane & 15, er = (lane >> 4) * 4;

  if (bid >= 160) {
    // ---- ux co-block: one 128^2 tile of slab s+2 ----
    const int q = bid - 160;
    const int slab = s + 2;
    const int rbu = (q >> 4) * 128, cbu = (q & 15) * 128;
    f32x4 acc[4][4] = {};
    gemm_core(x16s + (size_t)slab * 1280 * 768, U16p, 768, rbu, cbu, shAll, acc);
    f16* C = uxout + (size_t)slab * 1280 * 2048;
#pragma unroll
    for (int m = 0; m < 4; ++m)
#pragma unroll
      for (int n = 0; n < 4; ++n) {
        const int c = cbu + wc + n * 16 + ec;
#pragma unroll
        for (int j = 0; j < 4; ++j)
          C[(size_t)(rbu + wr + m * 16 + er + j) * 2048 + c] = (f16)acc[m][n][j];
      }
    return;
  }

  // ---- step path (R6/R10/R11-verified) ----
  f16x8* shA = shAll;
  f16x8* shB = shAll + 2048;
  f16x8* shC = shAll + 4096;
  f16x8* shD = shAll + 6144;
  f16x8* shU = shAll + 6656;
  f16x8* shE = shAll + 8704;
  const int rb = (bid >> 4) * 128;
  const int cg = bid & 15;
  const int rr = lane & 15, chb = lane >> 4;
  const int h = cg * 32 + (w & 1) * 16 + ec;
  const int hcol = (w & 1) * 16 + ec;
  const f16* Ah = hin + (size_t)rb * 512;
  const f16* Ac = cin16 + (size_t)rb * 512;
  const f16* Bw = Wallp + (size_t)cg * 128 * 512;
  const f16* Bd = Wd16 + (size_t)cg * 32 * 512;
  const f16* uxs = ux + (size_t)s * 1280 * 2048;
  float bW[4];
#pragma unroll
  for (int n = 0; n < 4; ++n) bW[n] = ballp[cg * 128 + wc + n * 16 + ec];
  const float bD = Wd_b[h];
  const f16* shUf = (const f16*)shU;
  const float* shEf = (const float*)shE;
  const int kbase = (wc >> 3) + (ec >> 3);
  f32x4 acc[4][4] = {};
  f32x4 acc2[4] = {};

  auto stage128 = [&](f16x8* dstBase, const f16* src, int k0) {
#pragma unroll
    for (int i = 0; i < 4; ++i) {
      int c = i * 256 + t; int r = c >> 3; int cc = (c & 7) ^ (r & 7);
      gload16(src + (size_t)r * 512 + (k0 + cc * 8), dstBase + i * 256 + (t & 192));
    }
  };
  auto stage32 = [&](f16x8* dstBase, const f16* src, int k0) {
    const int r = t >> 3; const int cc = (t & 7) ^ (r & 7);
    gload16(src + (size_t)r * 512 + (k0 + cc * 8), dstBase + (t & 192));
  };
  auto stageU = [&]() {   // s-major slab: row (rb+lr), stride 2048
#pragma unroll
    for (int i = 0; i < 8; ++i) {
      int c = i * 256 + t; int lr = c >> 4; int k = c & 15;
      int klog = k ^ (((lr >> 2) & 3) << 1);
      gload16(uxs + (size_t)(rb + lr) * 2048 + cg * 128 + klog * 8, shU + i * 256 + (t & 192));
    }
  };
  auto stageE = [&]() {
#pragma unroll
    for (int i = 0; i < 4; ++i) {
      int c = i * 256 + t; int lr = c >> 3; int k = c & 7;
      int klog = k ^ (((lr >> 2) & 1) << 2);
      gload16((const f16*)(cin32 + (size_t)(rb + lr) * 512 + cg * 32 + klog * 4),
              shE + i * 256 + (t & 192));
    }
  };

  if (s == 0) {
    stageU();
    stageE();
    asm volatile("s_waitcnt vmcnt(0)" ::: "memory");
    __builtin_amdgcn_s_barrier();
  } else {
    stage128(shA, Ah, 0);
    stage128(shB, Bw, 0);
    stage128(shC, Ac, 0);
    stage32(shD, Bd, 0);
    stageU();
    stageE();
    for (int kt = 0; kt < 8; ++kt) {
      const int cur = kt & 1;
      if (kt < 7) {
        stage128(shA + (cur ^ 1) * 1024, Ah, (kt + 1) * 64);
        stage128(shB + (cur ^ 1) * 1024, Bw, (kt + 1) * 64);
        stage128(shC + (cur ^ 1) * 1024, Ac, (kt + 1) * 64);
        stage32(shD + (cur ^ 1) * 256, Bd, (kt + 1) * 64);
        asm volatile("s_waitcnt vmcnt(13)" ::: "memory");
      } else {
        asm volatile("s_waitcnt vmcnt(0)" ::: "memory");
      }
      __builtin_amdgcn_s_barrier();
      __builtin_amdgcn_sched_barrier(0);
      const f16x8* pA = shA + cur * 1024;
      const f16x8* pB = shB + cur * 1024;
      const f16x8* pC = shC + cur * 1024;
      const f16x8* pD = shD + cur * 256;
#pragma unroll
      for (int kk = 0; kk < 2; ++kk) {
        const int ch = kk * 4 + chb;
        f16x8 af[4], bf[4], cf[4], df;
#pragma unroll
        for (int m = 0; m < 4; ++m) {
          const int row = wr + m * 16 + rr;
          af[m] = pA[row * 8 + (ch ^ (row & 7))];
          cf[m] = pC[row * 8 + (ch ^ (row & 7))];
        }
#pragma unroll
        for (int n = 0; n < 4; ++n) { const int row = wc + n * 16 + rr; bf[n] = pB[row * 8 + (ch ^ (row & 7))]; }
        { const int row = (w & 1) * 16 + rr; df = pD[row * 8 + (ch ^ (row & 7))]; }
#pragma unroll
        for (int m = 0; m < 4; ++m) {
#pragma unroll
          for (int n = 0; n < 4; ++n)
            acc[m][n] = __builtin_amdgcn_mfma_f32_16x16x32_f16(af[m], bf[n], acc[m][n], 0, 0, 0);
          acc2[m] = __builtin_amdgcn_mfma_f32_16x16x32_f16(cf[m], df, acc2[m], 0, 0, 0);
        }
      }
      __builtin_amdgcn_sched_barrier(0);
      __builtin_amdgcn_s_barrier();
    }
  }

  // epilogue: full cell update; ux/c32 from swizzled LDS, tf from tft. (verified R5/R6/R10/R11)
#pragma unroll
  for (int m = 0; m < 4; ++m)
#pragma unroll
    for (int j = 0; j < 4; ++j) {
      const int lr = wr + m * 16 + er + j;
      const int r = rb + lr;
      const float tv = tft[s * 1280 + r];
      const int sU = ((lr >> 2) & 3) << 1;
      const float u0 = (float)shUf[(lr * 16 + ((kbase + 0) ^ sU)) * 8 + (ec & 7)];
      const float u1 = (float)shUf[(lr * 16 + ((kbase + 2) ^ sU)) * 8 + (ec & 7)];
      const float u2v = (float)shUf[(lr * 16 + ((kbase + 4) ^ sU)) * 8 + (ec & 7)];
      const float u3 = (float)shUf[(lr * 16 + ((kbase + 6) ^ sU)) * 8 + (ec & 7)];
      const float p0 = acc[m][0][j] + bW[0] + u0;
      const float p1 = acc[m][1][j] + bW[1] + u1;
      const float p2 = acc[m][2][j] + bW[2] + u2v;
      const float p3 = acc[m][3][j] + bW[3] + u3;
      const float f = sigf(p0), i = sigf(p1), o = sigf(p2), ct = sigf(p3);
      const float cs = tanhfast(acc2[m][j] + bD);
      const int sE = ((lr >> 2) & 1) << 2;
      const float c_old = shEf[(lr * 8 + ((hcol >> 2) ^ sE)) * 4 + (hcol & 3)];
      const float cadj = c_old - cs + cs * tv;
      const float cn = f * cadj + i * ct;
      cout32[(size_t)r * 512 + h] = cn;
      cout16[(size_t)r * 512 + h] = (f16)cn;
      hout[(size_t)r * 512 + h] = (f16)(o * tanhfast(cn));
      outs[((size_t)r * 30 + s) * 512 + h] = (f16)o;
    }
}

// ---------------- fused lstm2 step ----------------
__global__ __launch_bounds__(256, 2) void k_l2step(const f16* __restrict__ hin, const f16* __restrict__ Whhp,
    const float* __restrict__ xi2, const float* __restrict__ cin, float* __restrict__ cout,
    f16* __restrict__ hout, float* __restrict__ l2o32, f16* __restrict__ l2o16, int ts) {
  __shared__ f16x8 sh[4096];
  const int rb = (blockIdx.x >> 4) * 128, cg = blockIdx.x & 15;
  f32x4 acc[4][4] = {};
  gemm_core(hin, Whhp, 512, rb, cg * 128, sh, acc);
  const int t = threadIdx.x, lane = t & 63, w = t >> 6;
  const int wr = (w >> 1) * 64, wc = (w & 1) * 64, ec = lane & 15, er = (lane >> 4) * 4;
  const int h = cg * 32 + (w & 1) * 16 + ec;
#pragma unroll
  for (int m = 0; m < 4; ++m)
#pragma unroll
    for (int j = 0; j < 4; ++j) {
      const int r = rb + wr + m * 16 + er + j;
      const size_t xb = ((size_t)r * 5 + ts) * 2048 + cg * 128 + wc + ec;
      const float p0 = acc[m][0][j] + xi2[xb];
      const float p1 = acc[m][1][j] + xi2[xb + 16];
      const float p2 = acc[m][2][j] + xi2[xb + 32];
      const float p3 = acc[m][3][j] + xi2[xb + 48];
      const float ii = sigf(p0), ff = sigf(p1), gg = tanhfast(p2), oo = sigf(p3);
      const float cn = ff * cin[(size_t)r * 512 + h] + ii * gg;
      const float hn = oo * tanhfast(cn);
      cout[(size_t)r * 512 + h] = cn;
      hout[(size_t)r * 512 + h] = (f16)hn;
      const size_t ob = ((size_t)r * 5 + ts) * 512 + h;
      l2o32[ob] = hn;
      l2o16[ob] = (f16)hn;
    }
}

// w1last[d] = A1_W1 @ outs[d, B-1, len-1] + b
__global__ __launch_bounds__(256) void k_w1last(const f16* __restrict__ outs, const int* __restrict__ lens,
                                                const float* __restrict__ W1, const float* __restrict__ W1b,
                                                float* __restrict__ w1l) {
  __shared__ float lastv[512];
  const int d = blockIdx.x;
  const int idx = lens[255 * 5 + d] - 1;
  const size_t row = ((size_t)(d * 256 + 255) * 30 + idx) * 512;
  for (int h = threadIdx.x; h < 512; h += 256) lastv[h] = (float)outs[row + h];
  __syncthreads();
  for (int h = threadIdx.x; h < 512; h += 256) {
    const float* wr = W1 + (size_t)h * 512;
    float p = W1b[h];
    for (int k = 0; k < 512; ++k) p += lastv[k] * wr[k];
    w1l[d * 512 + h] = p;
  }
}

// attn1 softmax + weighted sum
__global__ __launch_bounds__(256) void k_attn1(const float* __restrict__ score, const f16* __restrict__ outs,
                                               const int* __restrict__ lens,
                                               float* __restrict__ l1o32, f16* __restrict__ l1o16) {
  __shared__ float saw[32];
  const int n = blockIdx.x;
  const int d = n >> 8, b = n & 255;
  const int len = lens[b * 5 + d];
  const int t = threadIdx.x, lane = t & 63, w = t >> 6;
  if (w == 0) {
    const bool valid = lane < len;
    float sc = valid ? score[(size_t)n * 30 + lane] : -INFINITY;
    float mx = sc;
#pragma unroll
    for (int off = 32; off > 0; off >>= 1) mx = fmaxf(mx, __shfl_xor(mx, off));
    float e = valid ? __expf(sc - mx) : 0.f;
    float sm = e;
#pragma unroll
    for (int off = 32; off > 0; off >>= 1) sm += __shfl_xor(sm, off);
    if (lane < 30) saw[lane] = e / sm;
  }
  __syncthreads();
  for (int h = t; h < 512; h += 256) {
    float acc = 0.f;
    for (int s = 0; s < len; ++s) acc += saw[s] * (float)outs[((size_t)n * 30 + s) * 512 + h];
    const size_t o = ((size_t)b * 5 + d) * 512 + h;
    l1o32[o] = acc;
    l1o16[o] = (f16)acc;
  }
}

// merged u2/v2 GEMMs for attn2
__global__ __launch_bounds__(256, 2) void k_uv(const f16* __restrict__ l2o16, const f16* __restrict__ A2W2c,
    const f16* __restrict__ h2fin, const f16* __restrict__ A2W1c,
    const float* __restrict__ bu, const float* __restrict__ bv,
    float* __restrict__ u2, float* __restrict__ v2) {
  __shared__ f16x8 sh[4096];
  const int bid = blockIdx.x;
  const f16* A; const f16* B; const float* bias; float* out; int rb, cb;
  if (bid < 40) { A = l2o16; B = A2W2c; bias = bu; out = u2; rb = (bid >> 2) * 128; cb = (bid & 3) * 128; }
  else { int b2 = bid - 40; A = h2fin; B = A2W1c; bias = bv; out = v2; rb = (b2 >> 2) * 128; cb = (b2 & 3) * 128; }
  f32x4 acc[4][4] = {};
  gemm_core(A, B, 512, rb, cb, sh, acc);
  const int t = threadIdx.x, lane = t & 63, w = t >> 6;
  const int wr = (w >> 1) * 64, wc = (w & 1) * 64, ec = lane & 15, er = (lane >> 4) * 4;
#pragma unroll
  for (int m = 0; m < 4; ++m)
#pragma unroll
    for (int n = 0; n < 4; ++n) {
      const int c = cb + wc + n * 16 + ec;
      const float bvv = bias[c];
#pragma unroll
      for (int j = 0; j < 4; ++j) out[(size_t)(rb + wr + m * 16 + er + j) * 512 + c] = acc[m][n][j] + bvv;
    }
}

// attn2 over D=5 days
__global__ __launch_bounds__(256) void k_attn2(const float* __restrict__ u2, const float* __restrict__ v2,
                                               const float* __restrict__ l2o, const float* __restrict__ V2,
                                               const float* __restrict__ V2b, f16* __restrict__ ctx16) {
  __shared__ float ssc[8];
  __shared__ float saw[8];
  const int b = blockIdx.x;
  const int t = threadIdx.x, lane = t & 63, w = t >> 6;
  for (int tt = w; tt < 5; tt += 4) {
    const float* ur = u2 + ((size_t)b * 5 + tt) * 512;
    const float* vr = v2 + (size_t)b * 512;
    float p = 0.f;
#pragma unroll
    for (int j = 0; j < 8; ++j) { int h = lane * 8 + j; p += V2[h] * tanhfast(ur[h] + vr[h]); }
#pragma unroll
    for (int off = 32; off > 0; off >>= 1) p += __shfl_down(p, off);
    if (lane == 0) ssc[tt] = p + V2b[0];
  }
  __syncthreads();
  if (w == 0) {
    const bool valid = lane < 5;
    float sc = valid ? ssc[lane] : -INFINITY;
    float mx = sc;
#pragma unroll
    for (int off = 32; off > 0; off >>= 1) mx = fmaxf(mx, __shfl_xor(mx, off));
    float e = valid ? __expf(sc - mx) : 0.f;
    float sm = e;
#pragma unroll
    for (int off = 32; off > 0; off >>= 1) sm += __shfl_xor(sm, off);
    if (valid) saw[lane] = e / sm;
  }
  __syncthreads();
  for (int h = t; h < 512; h += 256) {
    float a = 0.f;
#pragma unroll
    for (int tt = 0; tt < 5; ++tt) a += saw[tt] * l2o[((size_t)b * 5 + tt) * 512 + h];
    ctx16[(size_t)b * 512 + h] = (f16)a;
  }
}

// final: out = h3 @ lin4^T + b4
__global__ __launch_bounds__(256) void k_final(const float* __restrict__ h3, const float* __restrict__ W4,
                                               const float* __restrict__ b4, float* __restrict__ out) {
  const int idx = blockIdx.x * 256 + threadIdx.x;
  const int b = idx >> 1, o = idx & 1;
  const float* hr = h3 + b * 256;
  const float* wr = W4 + o * 256;
  float p = b4[o];
  for (int j = 0; j < 256; ++j) p += hr[j] * wr[j];
  out[idx] = p;
}

// ---------------- prep kernels ----------------
// cast sentence_feats to s-major x16s[s][n][768], n = d*256+b
__global__ __launch_bounds__(256) void k_castx(const float* __restrict__ sf, f16* __restrict__ x16s) {
  const int total = 7372800;  // 38400*768/4
  for (int e = blockIdx.x * 256 + threadIdx.x; e < total; e += gridDim.x * 256) {
    const int row = e / 192, k = e - row * 192;
    const int b = row / 150, rem = row - b * 150;
    const int d = rem / 30, s = rem - d * 30;
    const int orow = s * 1280 + d * 256 + b;
    const float4 v = ((const float4*)sf)[e];
    f16x4 o = {(f16)v.x, (f16)v.y, (f16)v.z, (f16)v.w};
    ((f16x4*)x16s)[(size_t)orow * 192 + k] = o;
  }
}

// merged weight cast (+optional gate permutation)
struct WPArgs { const float* src[9]; f16* dst[9]; int k4[9]; int cnt4[9]; int perm[9]; };
__global__ __launch_bounds__(256) void k_castwp(WPArgs a) {
  int g = blockIdx.x * 256 + threadIdx.x;
#pragma unroll
  for (int si = 0; si < 9; ++si) {
    if (g < a.cnt4[si]) {
      const int K4 = a.k4[si];
      const int c = g / K4, k = g - c * K4;
      const int srow = a.perm[si] ? permrow(c) : c;
      const float4 v = ((const float4*)a.src[si])[(size_t)srow * K4 + k];
      f16x4 o = {(f16)v.x, (f16)v.y, (f16)v.z, (f16)v.w};
      ((f16x4*)a.dst[si])[(size_t)c * K4 + k] = o;
      return;
    }
    g -= a.cnt4[si];
  }
}

// state init + tft + score. PERSISTENT/FRESH regions ONLY — must NOT touch the x16s overlay
// (R8/R9 bug: zeroing h2/c2 here clobbered live x16s rows 9493-10352).
__global__ __launch_bounds__(256) void k_zero(f16* h16a, f16* c16a, float* c32a,
    float* ballp, float* bihp, const float* Wall_b, const float* Uall_b,
    const float* bih, const float* bhh, float* tft, const float* tf,
    float* score, const float* Vb) {
  const int i = blockIdx.x * 256 + threadIdx.x;
  if (i < 655360) { h16a[i] = (f16)0.f; c16a[i] = (f16)0.f; c32a[i] = 0.f; }
  if (i < 2048) {
    const int p = permrow(i);
    ballp[i] = Wall_b[p] + Uall_b[p];
    bihp[i] = bih[p] + bhh[p];
  }
  if (i < 38400) {
    const int s = i / 1280, r = i - s * 1280;
    const int d = r >> 8, b = r & 255;
    tft[i] = tf[((size_t)b * 5 + d) * 30 + s];
    score[i] = Vb[0];
  }
}

// lstm2 state init — runs AFTER the recurrence (x16s dead), h2/c2 live in the overlay region
__global__ __launch_bounds__(256) void k_init2(f16* h2a, float* c2a) {
  const int i = blockIdx.x * 256 + threadIdx.x;
  if (i < 131072) { h2a[i] = (f16)0.f; c2a[i] = 0.f; }
}

// ---------------- launch ----------------
extern "C" void kernel_launch(void* const* d_in, const int* in_sizes, int n_in,
                              void* d_out, int out_size, void* d_ws, size_t ws_size,
                              hipStream_t stream) {
  const float* sf     = (const float*)d_in[0];
  const float* tf     = (const float*)d_in[1];
  const int*   lens   = (const int*)d_in[2];
  const float* Wd_w   = (const float*)d_in[3];
  const float* Wd_b   = (const float*)d_in[4];
  const float* Wall_w = (const float*)d_in[5];
  const float* Wall_b = (const float*)d_in[6];
  const float* Uall_w = (const float*)d_in[7];
  const float* Uall_b = (const float*)d_in[8];
  const float* A1W1   = (const float*)d_in[9];
  const float* A1W1b  = (const float*)d_in[10];
  const float* A1W2   = (const float*)d_in[11];
  const float* A1W2b  = (const float*)d_in[12];
  const float* A1V    = (const float*)d_in[13];
  const float* A1Vb   = (const float*)d_in[14];
  const float* Wih    = (const float*)d_in[15];
  const float* Whh    = (const float*)d_in[16];
  const float* bih    = (const float*)d_in[17];
  const float* bhh    = (const float*)d_in[18];
  const float* A2W1   = (const float*)d_in[19];
  const float* A2W1b  = (const float*)d_in[20];
  const float* A2W2   = (const float*)d_in[21];
  const float* A2W2b  = (const float*)d_in[22];
  const float* A2V    = (const float*)d_in[23];
  const float* A2Vb   = (const float*)d_in[24];
  const float* L3w    = (const float*)d_in[25];
  const float* L3b    = (const float*)d_in[26];
  const float* L4w    = (const float*)d_in[27];
  const float* L4b    = (const float*)d_in[28];

  if (ws_size < WS_NEED) return;
  char* ws = (char*)d_ws;
  f16*   x16s   = (f16*)(ws + OFF_X16);
  f16*   ux16   = (f16*)(ws + OFF_UX);
  f16*   outs16 = (f16*)(ws + OFF_OUTS);
  f16*   Wd16   = (f16*)(ws + OFF_WD);
  f16*   Wallp  = (f16*)(ws + OFF_WALLP);
  f16*   U16p   = (f16*)(ws + OFF_UP);
  f16*   W216   = (f16*)(ws + OFF_W2);
  f16*   Wihp   = (f16*)(ws + OFF_WIHP);
  f16*   Whhp   = (f16*)(ws + OFF_WHHP);
  f16*   A2W116 = (f16*)(ws + OFF_A2W1C);
  f16*   A2W216 = (f16*)(ws + OFF_A2W2C);
  f16*   L316   = (f16*)(ws + OFF_L3WC);
  float* ballp  = (float*)(ws + OFF_BALLP);
  float* bihp   = (float*)(ws + OFF_BIHP);
  f16*   h16b[2]  = {(f16*)(ws + OFF_H16), (f16*)(ws + OFF_H16 + 1310720)};
  f16*   c16b[2]  = {(f16*)(ws + OFF_C16), (f16*)(ws + OFF_C16 + 1310720)};
  float* c32b[2]  = {(float*)(ws + OFF_C32), (float*)(ws + OFF_C32 + 2621440)};
  float* tft    = (float*)(ws + OFF_TFTN);
  float* score  = (float*)(ws + OFF_SCOREN);
  float* w1l    = (float*)(ws + OFF_W1L);
  float* l1o32  = (float*)(ws + OFF_L1O32);
  f16*   l1o16  = (f16*)(ws + OFF_L1O16);
  float* xi2    = (float*)(ws + OFF_XI2);
  float* c2b[2] = {(float*)(ws + OFF_C2), (float*)(ws + OFF_C2 + 524288)};
  f16*   h2b[2] = {(f16*)(ws + OFF_H2), (f16*)(ws + OFF_H2 + 262144)};
  float* l2o32  = (float*)(ws + OFF_L2O32);
  f16*   l2o16  = (f16*)(ws + OFF_L2O16);
  float* u2     = (float*)(ws + OFF_U2);
  float* v2     = (float*)(ws + OFF_V2);
  f16*   ctx16  = (f16*)(ws + OFF_CTX16);
  float* h3     = (float*)(ws + OFF_H3);

  // 1. input casts + init (k_zero touches ONLY persistent/fresh regions — x16s stays intact)
  k_castx<<<2048, 256, 0, stream>>>(sf, x16s);
  WPArgs wa;
  wa.src[0] = Wd_w;   wa.dst[0] = Wd16;   wa.k4[0] = 128; wa.cnt4[0] = 65536;  wa.perm[0] = 0;
  wa.src[1] = A1W2;   wa.dst[1] = W216;   wa.k4[1] = 128; wa.cnt4[1] = 65536;  wa.perm[1] = 0;
  wa.src[2] = A2W1;   wa.dst[2] = A2W116; wa.k4[2] = 128; wa.cnt4[2] = 65536;  wa.perm[2] = 0;
  wa.src[3] = A2W2;   wa.dst[3] = A2W216; wa.k4[3] = 128; wa.cnt4[3] = 65536;  wa.perm[3] = 0;
  wa.src[4] = L3w;    wa.dst[4] = L316;   wa.k4[4] = 128; wa.cnt4[4] = 32768;  wa.perm[4] = 0;
  wa.src[5] = Wall_w; wa.dst[5] = Wallp;  wa.k4[5] = 128; wa.cnt4[5] = 262144; wa.perm[5] = 1;
  wa.src[6] = Uall_w; wa.dst[6] = U16p;   wa.k4[6] = 192; wa.cnt4[6] = 393216; wa.perm[6] = 1;
  wa.src[7] = Wih;    wa.dst[7] = Wihp;   wa.k4[7] = 128; wa.cnt4[7] = 262144; wa.perm[7] = 1;
  wa.src[8] = Whh;    wa.dst[8] = Whhp;   wa.k4[8] = 128; wa.cnt4[8] = 262144; wa.perm[8] = 1;
  k_castwp<<<5760, 256, 0, stream>>>(wa);
  k_zero<<<2560, 256, 0, stream>>>(h16b[0], c16b[0], c32b[0], ballp, bihp, Wall_b, Uall_b, bih, bhh,
                                   tft, tf, score, A1Vb);

  // 2. ux prologue: slabs 0,1 (rows 0..2559 of s-major layout), 256^2 tiles
  k_gemm256<<<dim3(8, 10), 512, 0, stream>>>(x16s, U16p, 768, 2048, ux16);

  // 3. TimeLSTM recurrence: 30 launches; each carries the ux GEMM for slab s+2
  //    on the 96 CUs the 160-block step grid leaves idle.
  for (int s = 0; s < 30; ++s) {
    const int pi = s & 1, po = pi ^ 1;
    const int nb = (s <= 27) ? 320 : 160;
    k_stepm<<<nb, 256, 0, stream>>>(h16b[pi], c16b[pi], c32b[pi], Wallp, Wd16, ux16, ballp, Wd_b, tft,
                                    c32b[po], c16b[po], h16b[po], outs16,
                                    x16s, U16p, ux16, s);
  }

  // 4. lstm2 state init (x16s now dead; h2/c2 live in the overlay region)
  k_init2<<<512, 256, 0, stream>>>(h2b[0], c2b[0]);

  // 5. attn1 (score GEMM on the 128^2 core, 2 blocks/CU, 1200-block grid — no tail)
  k_w1last<<<5, 256, 0, stream>>>(outs16, lens, A1W1, A1W1b, w1l);
  k_score<<<dim3(4, 300), 256, 0, stream>>>(outs16, W216, A1W2b, w1l, A1V, score);
  k_attn1<<<1280, 256, 0, stream>>>(score, outs16, lens, l1o32, l1o16);

  // 6. lstm2: xi2 (permuted cols, biases folded), then 5 fused steps
  k_gemm<0, true, false><<<dim3(16, 10), 256, 0, stream>>>(l1o16, Wihp, 512, 2048, bihp, xi2, nullptr);
  for (int ts = 0; ts < 5; ++ts) {
    const int pi = ts & 1, po = pi ^ 1;
    k_l2step<<<32, 256, 0, stream>>>(h2b[pi], Whhp, xi2, c2b[pi], c2b[po], h2b[po], l2o32, l2o16, ts);
  }

  // 7. attn2 (h2 final is buffer 1 after 5 steps)
  k_uv<<<48, 256, 0, stream>>>(l2o16, A2W216, h2b[1], A2W116, A2W2b, A2W1b, u2, v2);
  k_attn2<<<256, 256, 0, stream>>>(u2, v2, l2o32, A2V, A2Vb, ctx16);

  // 8. head
  k_gemm<3, true, false><<<dim3(2, 2), 256, 0, stream>>>(ctx16, L316, 512, 256, L3b, h3, nullptr);
  k_final<<<2, 256, 0, stream>>>(h3, L4w, L4b, (float*)d_out);
}

// Round 13
// 918.836 us; speedup vs baseline: 1.1087x; 1.0075x over previous
//
#include <hip/hip_runtime.h>
#include <math.h>

typedef _Float16 f16;
typedef _Float16 f16x4 __attribute__((ext_vector_type(4)));
typedef _Float16 f16x8 __attribute__((ext_vector_type(8)));
typedef float f32x4 __attribute__((ext_vector_type(4)));

#define DEV static __device__ __forceinline__

// ---------------- workspace layout (byte offsets; all 256-aligned) ----------------
// persistent region
#define OFF_X16    ((size_t)0)            // x16s [s][n][768] f16 (live until launch 27; tail overlays after)
#define OFF_UX     ((size_t)58982400)     // ux16 [s][n][2048] f16 s-major (permuted cols)
#define OFF_OUTS   ((size_t)216268800)    // outs16 38400x512 f16 (n*30+s row layout)
#define OFF_WD     ((size_t)255590400)    // Wd16 512x512
#define OFF_WALLP  ((size_t)256114688)    // Wall16 permuted 2048x512
#define OFF_UP     ((size_t)258211840)    // Uall16 permuted 2048x768
#define OFF_W2     ((size_t)261357568)    // A1_W2 512x512
#define OFF_WIHP   ((size_t)261881856)    // Wih16 permuted 2048x512
#define OFF_WHHP   ((size_t)263979008)    // Whh16 permuted 2048x512
#define OFF_A2W1C  ((size_t)266076160)    // A2_W1 512x512
#define OFF_A2W2C  ((size_t)266600448)    // A2_W2 512x512
#define OFF_L3WC   ((size_t)267124736)    // lin3 256x512
#define OFF_BALLP  ((size_t)267386880)    // permuted Wall_b+Uall_b 2048 f32
#define OFF_BIHP   ((size_t)267395072)    // permuted bih+bhh 2048 f32
#define OFF_H16    ((size_t)267403264)    // h16 ping-pong 2x 1280x512 f16
#define OFF_C16    ((size_t)270024704)    // c16 ping-pong
#define OFF_C32    ((size_t)272646144)    // c32 ping-pong 2x 1280x512 f32
#define OFF_TFTN   ((size_t)277889024)    // tft[s][r] 30x1280 f32 (fresh region)
#define OFF_SCOREN (OFF_TFTN + 153600)    // score 38400 f32 (fresh region)
#define WS_NEED    (OFF_SCOREN + 153600)
// tail region overlays X16 (x16s dead after launch 27; ALL writes below happen after the recurrence)
#define OFF_W1L    ((size_t)153600)       // 5x512 f32
#define OFF_L1O32  ((size_t)163840)       // 1280x512 f32
#define OFF_L1O16  ((size_t)2785280)      // 1280x512 f16
#define OFF_XI2    ((size_t)4096000)      // 1280x2048 f32 (permuted cols, biases included)
#define OFF_C2     ((size_t)14581760)     // ping-pong 2x 256x512 f32   (init by k_init2 AFTER recurrence)
#define OFF_H2     ((size_t)15630336)     // ping-pong 2x 256x512 f16   (init by k_init2 AFTER recurrence)
#define OFF_L2O32  ((size_t)16154624)     // 1280x512 f32
#define OFF_L2O16  ((size_t)18776064)     // f16
#define OFF_U2     ((size_t)20086784)     // 1280x512 f32
#define OFF_V2     ((size_t)22708224)     // 256x512 f32
#define OFF_CTX16  ((size_t)23232512)     // 256x512 f16
#define OFF_H3     ((size_t)23494656)     // 256x256 f32

DEV float sigf(float x) { return 1.f / (1.f + __expf(-x)); }
DEV float tanhfast(float x) { float e = __expf(2.f * x); return 1.f - 2.f / (e + 1.f); }
// permuted col c' -> original row g*512+h, g=(c'>>4)&3, h=(c'>>6)*16+(c'&15)
DEV int permrow(int c) { return (((c >> 4) & 3) << 9) | ((c >> 6) << 4) | (c & 15); }

DEV void gload16(const f16* g, f16x8* lds) {
  __builtin_amdgcn_global_load_lds((const __attribute__((address_space(1))) void*)g,
                                   (__attribute__((address_space(3))) void*)lds, 16, 0, 0);
}

// ---------------- 128x128 fp16 MFMA GEMM core (counted-vmcnt 2-barrier, 4 waves) ----------------
DEV void gemm_core(const f16* __restrict__ A, const f16* __restrict__ Bt, int K,
                   int rowBase, int colBase, f16x8* sh, f32x4 (&acc)[4][4]) {
  const int t = threadIdx.x, lane = t & 63, w = t >> 6;
  const int wr = (w >> 1) * 64, wc = (w & 1) * 64;
  const f16* Arow = A + (size_t)rowBase * K;
  const f16* Brow = Bt + (size_t)colBase * K;
  auto stage = [&](f16x8* dstBase, const f16* src, int k0) {
#pragma unroll
    for (int i = 0; i < 4; ++i) {
      int c = i * 256 + t; int r = c >> 3; int cc = (c & 7) ^ (r & 7);
      gload16(src + (size_t)r * K + (k0 + cc * 8), dstBase + i * 256 + (t & 192));
    }
  };
  stage(sh, Arow, 0);
  stage(sh + 2048, Brow, 0);
  const int nk = K >> 6;
  for (int kt = 0; kt < nk; ++kt) {
    const int cur = kt & 1;
    if (kt + 1 < nk) {
      stage(sh + (cur ^ 1) * 1024, Arow, (kt + 1) * 64);
      stage(sh + 2048 + (cur ^ 1) * 1024, Brow, (kt + 1) * 64);
      asm volatile("s_waitcnt vmcnt(8)" ::: "memory");
    } else {
      asm volatile("s_waitcnt vmcnt(0)" ::: "memory");
    }
    __builtin_amdgcn_s_barrier();
    __builtin_amdgcn_sched_barrier(0);
    const f16x8* shA = sh + cur * 1024;
    const f16x8* shB = sh + 2048 + cur * 1024;
    const int rr = lane & 15, chb = lane >> 4;
#pragma unroll
    for (int kk = 0; kk < 2; ++kk) {
      const int ch = kk * 4 + chb;
      f16x8 af[4], bf[4];
#pragma unroll
      for (int m = 0; m < 4; ++m) { int row = wr + m * 16 + rr; af[m] = shA[row * 8 + (ch ^ (row & 7))]; }
#pragma unroll
      for (int n = 0; n < 4; ++n) { int row = wc + n * 16 + rr; bf[n] = shB[row * 8 + (ch ^ (row & 7))]; }
#pragma unroll
      for (int m = 0; m < 4; ++m)
#pragma unroll
        for (int n = 0; n < 4; ++n)
          acc[m][n] = __builtin_amdgcn_mfma_f32_16x16x32_f16(af[m], bf[n], acc[m][n], 0, 0, 0);
    }
    __builtin_amdgcn_sched_barrier(0);
    __builtin_amdgcn_s_barrier();
  }
}

// ---------------- 256x256 fp16 MFMA GEMM core (8 waves; prologue only) ----------------
DEV void gemm_core256(const f16* __restrict__ A, const f16* __restrict__ Bt, int K,
                      int rowBase, int colBase, f16x8 (&shA)[2][2048], f16x8 (&shB)[2][2048],
                      f32x4 (&acc)[8][4]) {
  const int t = threadIdx.x, lane = t & 63, w = t >> 6;
  const int wm = w >> 2, wn = w & 3;       // 2 x 4 wave grid; wave owns 128x64
  const f16* Arow = A + (size_t)rowBase * K;
  const f16* Brow = Bt + (size_t)colBase * K;
  auto stage = [&](f16x8* dst, const f16* src, int k0) {
#pragma unroll
    for (int i = 0; i < 4; ++i) {
      int c = i * 512 + t; int r = c >> 3; int cc = (c & 7) ^ (r & 7);
      gload16(src + (size_t)r * K + (k0 + cc * 8), dst + i * 512 + (t & 448));
    }
  };
  stage(shA[0], Arow, 0);
  stage(shB[0], Brow, 0);
  const int nk = K >> 6;
  for (int kt = 0; kt < nk; ++kt) {
    const int cur = kt & 1;
    if (kt + 1 < nk) {
      stage(shA[cur ^ 1], Arow, (kt + 1) * 64);
      stage(shB[cur ^ 1], Brow, (kt + 1) * 64);
      asm volatile("s_waitcnt vmcnt(8)" ::: "memory");
    } else {
      asm volatile("s_waitcnt vmcnt(0)" ::: "memory");
    }
    __builtin_amdgcn_s_barrier();
    __builtin_amdgcn_sched_barrier(0);
    const f16x8* pA = shA[cur];
    const f16x8* pB = shB[cur];
    const int rr = lane & 15, chb = lane >> 4;
#pragma unroll
    for (int kk = 0; kk < 2; ++kk) {
      const int ch = kk * 4 + chb;
      f16x8 bf[4];
#pragma unroll
      for (int n = 0; n < 4; ++n) { int row = wn * 64 + n * 16 + rr; bf[n] = pB[row * 8 + (ch ^ (row & 7))]; }
#pragma unroll
      for (int m = 0; m < 8; ++m) {
        int row = wm * 128 + m * 16 + rr;
        f16x8 af = pA[row * 8 + (ch ^ (row & 7))];
#pragma unroll
        for (int n = 0; n < 4; ++n)
          acc[m][n] = __builtin_amdgcn_mfma_f32_16x16x32_f16(af, bf[n], acc[m][n], 0, 0, 0);
      }
    }
    __builtin_amdgcn_sched_barrier(0);
    __builtin_amdgcn_s_barrier();
  }
}

// prologue ux GEMM (slabs 0,1): 256^2 tile, f16 out. grid (N/256, rows/256)
__global__ __launch_bounds__(512, 1) void k_gemm256(const f16* __restrict__ A, const f16* __restrict__ Bt,
                                                    int K, int N, f16* __restrict__ C16) {
  __shared__ f16x8 shA[2][2048];
  __shared__ f16x8 shB[2][2048];
  const int rb = blockIdx.y * 256, cb = blockIdx.x * 256;
  f32x4 acc[8][4] = {};
  gemm_core256(A, Bt, K, rb, cb, shA, shB, acc);
  const int t = threadIdx.x, lane = t & 63, w = t >> 6;
  const int wm = w >> 2, wn = w & 3;
  const int ec = lane & 15, er = (lane >> 4) * 4;
#pragma unroll
  for (int m = 0; m < 8; ++m)
#pragma unroll
    for (int n = 0; n < 4; ++n) {
      const int c = cb + wn * 64 + n * 16 + ec;
#pragma unroll
      for (int j = 0; j < 4; ++j) {
        const int r = rb + wm * 128 + m * 16 + er + j;
        C16[(size_t)r * N + c] = (f16)acc[m][n][j];
      }
    }
}

// attn1 score fused into the 128^2 GEMM epilogue (R3-R6/R12 verified)
__global__ __launch_bounds__(256, 2) void k_score(const f16* __restrict__ outs, const f16* __restrict__ W2t,
    const float* __restrict__ W2b, const float* __restrict__ w1l, const float* __restrict__ V,
    float* __restrict__ score) {
  __shared__ f16x8 sh[4096];
  const int rb = blockIdx.y * 128, cb = blockIdx.x * 128;
  f32x4 acc[4][4] = {};
  gemm_core(outs, W2t, 512, rb, cb, sh, acc);
  const int t = threadIdx.x, lane = t & 63, w = t >> 6;
  const int wr = (w >> 1) * 64, wc = (w & 1) * 64, ec = lane & 15, er = (lane >> 4) * 4;
  float* sacc = (float*)sh;  // reuse LDS (gemm_core ends with a barrier)
  if (t < 128) sacc[t] = 0.f;
  __syncthreads();
#pragma unroll
  for (int m = 0; m < 4; ++m)
#pragma unroll
    for (int j = 0; j < 4; ++j) {
      const int lr = wr + m * 16 + er + j;
      const int r = rb + lr;
      const int d = (r / 30) >> 8;
      float p = 0.f;
#pragma unroll
      for (int n = 0; n < 4; ++n) {
        const int c = cb + wc + n * 16 + ec;
        p += V[c] * tanhfast(acc[m][n][j] + W2b[c] + w1l[d * 512 + c]);
      }
      p += __shfl_xor(p, 1); p += __shfl_xor(p, 2); p += __shfl_xor(p, 4); p += __shfl_xor(p, 8);
      if (ec == 0) atomicAdd(&sacc[lr], p);
    }
  __syncthreads();
  if (t < 128) atomicAdd(&score[rb + t], sacc[t]);
}

// ---------------- generic bias/act GEMM wrapper (2D grid, 128^2) ----------------
template <int ACT, bool O32, bool O16>
__global__ __launch_bounds__(256, 2) void k_gemm(const f16* __restrict__ A, const f16* __restrict__ Bt,
                                                 int K, int N, const float* __restrict__ bias,
                                                 float* __restrict__ C32, f16* __restrict__ C16) {
  __shared__ f16x8 sh[4096];
  const int rb = blockIdx.y * 128, cb = blockIdx.x * 128;
  f32x4 acc[4][4] = {};
  gemm_core(A, Bt, K, rb, cb, sh, acc);
  const int t = threadIdx.x, lane = t & 63, w = t >> 6;
  const int wr = (w >> 1) * 64, wc = (w & 1) * 64, ec = lane & 15, er = (lane >> 4) * 4;
#pragma unroll
  for (int m = 0; m < 4; ++m)
#pragma unroll
    for (int n = 0; n < 4; ++n) {
      const int c = cb + wc + n * 16 + ec;
      const float bv = bias ? bias[c] : 0.f;
#pragma unroll
      for (int j = 0; j < 4; ++j) {
        const int r = rb + wr + m * 16 + er + j;
        float v = acc[m][n][j] + bv;
        if (ACT == 3) v = fmaxf(v, 0.f);
        if (O32) C32[(size_t)r * N + c] = v;
        if (O16) C16[(size_t)r * N + c] = (f16)v;
      }
    }
}

// ---------------- merged TimeLSTM step + ux co-GEMM ----------------
// R11/R12-verified structure; NEW in R13: shU/shE issue moved into the k-loop (kt==0),
// so their 48KB/block drain no longer precedes the first MFMA. Wait schedule:
// kt0,kt1 -> vmcnt(25); kt2..kt6 -> vmcnt(13); kt7 -> vmcnt(0).
__global__ __launch_bounds__(256, 1) void k_stepm(
    const f16* __restrict__ hin, const f16* __restrict__ cin16, const float* __restrict__ cin32,
    const f16* __restrict__ Wallp, const f16* __restrict__ Wd16,
    const f16* __restrict__ ux, const float* __restrict__ ballp, const float* __restrict__ Wd_b,
    const float* __restrict__ tft,
    float* __restrict__ cout32, f16* __restrict__ cout16, f16* __restrict__ hout,
    f16* __restrict__ outs,
    const f16* __restrict__ x16s, const f16* __restrict__ U16p, f16* __restrict__ uxout, int s) {
  __shared__ f16x8 shAll[9728];   // 152 KB
  const int bid = (int)blockIdx.x;
  const int t = threadIdx.x, lane = t & 63, w = t >> 6;
  const int wr = (w >> 1) * 64, wc = (w & 1) * 64;
  const int ec = lane & 15, er = (lane >> 4) * 4;

  if (bid >= 160) {
    // ---- ux co-block: one 128^2 tile of slab s+2 ----
    const int q = bid - 160;
    const int slab = s + 2;
    const int rbu = (q >> 4) * 128, cbu = (q & 15) * 128;
    f32x4 acc[4][4] = {};
    gemm_core(x16s + (size_t)slab * 1280 * 768, U16p, 768, rbu, cbu, shAll, acc);
    f16* C = uxout + (size_t)slab * 1280 * 2048;
#pragma unroll
    for (int m = 0; m < 4; ++m)
#pragma unroll
      for (int n = 0; n < 4; ++n) {
        const int c = cbu + wc + n * 16 + ec;
#pragma unroll
        for (int j = 0; j < 4; ++j)
          C[(size_t)(rbu + wr + m * 16 + er + j) * 2048 + c] = (f16)acc[m][n][j];
      }
    return;
  }

  // ---- step path ----
  f16x8* shA = shAll;
  f16x8* shB = shAll + 2048;
  f16x8* shC = shAll + 4096;
  f16x8* shD = shAll + 6144;
  f16x8* shU = shAll + 6656;
  f16x8* shE = shAll + 8704;
  const int rb = (bid >> 4) * 128;
  const int cg = bid & 15;
  const int rr = lane & 15, chb = lane >> 4;
  const int h = cg * 32 + (w & 1) * 16 + ec;
  const int hcol = (w & 1) * 16 + ec;
  const f16* Ah = hin + (size_t)rb * 512;
  const f16* Ac = cin16 + (size_t)rb * 512;
  const f16* Bw = Wallp + (size_t)cg * 128 * 512;
  const f16* Bd = Wd16 + (size_t)cg * 32 * 512;
  const f16* uxs = ux + (size_t)s * 1280 * 2048;
  float bW[4];
#pragma unroll
  for (int n = 0; n < 4; ++n) bW[n] = ballp[cg * 128 + wc + n * 16 + ec];
  const float bD = Wd_b[h];
  const f16* shUf = (const f16*)shU;
  const float* shEf = (const float*)shE;
  const int kbase = (wc >> 3) + (ec >> 3);
  f32x4 acc[4][4] = {};
  f32x4 acc2[4] = {};

  auto stage128 = [&](f16x8* dstBase, const f16* src, int k0) {
#pragma unroll
    for (int i = 0; i < 4; ++i) {
      int c = i * 256 + t; int r = c >> 3; int cc = (c & 7) ^ (r & 7);
      gload16(src + (size_t)r * 512 + (k0 + cc * 8), dstBase + i * 256 + (t & 192));
    }
  };
  auto stage32 = [&](f16x8* dstBase, const f16* src, int k0) {
    const int r = t >> 3; const int cc = (t & 7) ^ (r & 7);
    gload16(src + (size_t)r * 512 + (k0 + cc * 8), dstBase + (t & 192));
  };
  auto stageU = [&]() {   // s-major slab: row (rb+lr), stride 2048
#pragma unroll
    for (int i = 0; i < 8; ++i) {
      int c = i * 256 + t; int lr = c >> 4; int k = c & 15;
      int klog = k ^ (((lr >> 2) & 3) << 1);
      gload16(uxs + (size_t)(rb + lr) * 2048 + cg * 128 + klog * 8, shU + i * 256 + (t & 192));
    }
  };
  auto stageE = [&]() {
#pragma unroll
    for (int i = 0; i < 4; ++i) {
      int c = i * 256 + t; int lr = c >> 3; int k = c & 7;
      int klog = k ^ (((lr >> 2) & 1) << 2);
      gload16((const f16*)(cin32 + (size_t)(rb + lr) * 512 + cg * 32 + klog * 4),
              shE + i * 256 + (t & 192));
    }
  };

  if (s == 0) {
    stageU();
    stageE();
    asm volatile("s_waitcnt vmcnt(0)" ::: "memory");
    __builtin_amdgcn_s_barrier();
  } else {
    stage128(shA, Ah, 0);
    stage128(shB, Bw, 0);
    stage128(shC, Ac, 0);
    stage32(shD, Bd, 0);
    for (int kt = 0; kt < 8; ++kt) {
      const int cur = kt & 1;
      if (kt < 7) {
        stage128(shA + (cur ^ 1) * 1024, Ah, (kt + 1) * 64);
        stage128(shB + (cur ^ 1) * 1024, Bw, (kt + 1) * 64);
        stage128(shC + (cur ^ 1) * 1024, Ac, (kt + 1) * 64);
        stage32(shD + (cur ^ 1) * 256, Bd, (kt + 1) * 64);
        if (kt == 0) { stageU(); stageE(); }   // issued AFTER kt1 prefetch; drains at kt2
        if (kt < 2) {
          asm volatile("s_waitcnt vmcnt(25)" ::: "memory");  // drains current ktile only (U/E in flight)
        } else {
          asm volatile("s_waitcnt vmcnt(13)" ::: "memory");  // kt2: drains U/E + kt2; kt3-6: drains current
        }
      } else {
        asm volatile("s_waitcnt vmcnt(0)" ::: "memory");
      }
      __builtin_amdgcn_s_barrier();
      __builtin_amdgcn_sched_barrier(0);
      const f16x8* pA = shA + cur * 1024;
      const f16x8* pB = shB + cur * 1024;
      const f16x8* pC = shC + cur * 1024;
      const f16x8* pD = shD + cur * 256;
#pragma unroll
      for (int kk = 0; kk < 2; ++kk) {
        const int ch = kk * 4 + chb;
        f16x8 af[4], bf[4], cf[4], df;
#pragma unroll
        for (int m = 0; m < 4; ++m) {
          const int row = wr + m * 16 + rr;
          af[m] = pA[row * 8 + (ch ^ (row & 7))];
          cf[m] = pC[row * 8 + (ch ^ (row & 7))];
        }
#pragma unroll
        for (int n = 0; n < 4; ++n) { const int row = wc + n * 16 + rr; bf[n] = pB[row * 8 + (ch ^ (row & 7))]; }
        { const int row = (w & 1) * 16 + rr; df = pD[row * 8 + (ch ^ (row & 7))]; }
#pragma unroll
        for (int m = 0; m < 4; ++m) {
#pragma unroll
          for (int n = 0; n < 4; ++n)
            acc[m][n] = __builtin_amdgcn_mfma_f32_16x16x32_f16(af[m], bf[n], acc[m][n], 0, 0, 0);
          acc2[m] = __builtin_amdgcn_mfma_f32_16x16x32_f16(cf[m], df, acc2[m], 0, 0, 0);
        }
      }
      __builtin_amdgcn_sched_barrier(0);
      __builtin_amdgcn_s_barrier();
    }
  }

  // epilogue: full cell update; ux/c32 from swizzled LDS, tf from tft. (verified R5/R6/R10-R12)
#pragma unroll
  for (int m = 0; m < 4; ++m)
#pragma unroll
    for (int j = 0; j < 4; ++j) {
      const int lr = wr + m * 16 + er + j;
      const int r = rb + lr;
      const float tv = tft[s * 1280 + r];
      const int sU = ((lr >> 2) & 3) << 1;
      const float u0 = (float)shUf[(lr * 16 + ((kbase + 0) ^ sU)) * 8 + (ec & 7)];
      const float u1 = (float)shUf[(lr * 16 + ((kbase + 2) ^ sU)) * 8 + (ec & 7)];
      const float u2v = (float)shUf[(lr * 16 + ((kbase + 4) ^ sU)) * 8 + (ec & 7)];
      const float u3 = (float)shUf[(lr * 16 + ((kbase + 6) ^ sU)) * 8 + (ec & 7)];
      const float p0 = acc[m][0][j] + bW[0] + u0;
      const float p1 = acc[m][1][j] + bW[1] + u1;
      const float p2 = acc[m][2][j] + bW[2] + u2v;
      const float p3 = acc[m][3][j] + bW[3] + u3;
      const float f = sigf(p0), i = sigf(p1), o = sigf(p2), ct = sigf(p3);
      const float cs = tanhfast(acc2[m][j] + bD);
      const int sE = ((lr >> 2) & 1) << 2;
      const float c_old = shEf[(lr * 8 + ((hcol >> 2) ^ sE)) * 4 + (hcol & 3)];
      const float cadj = c_old - cs + cs * tv;
      const float cn = f * cadj + i * ct;
      cout32[(size_t)r * 512 + h] = cn;
      cout16[(size_t)r * 512 + h] = (f16)cn;
      hout[(size_t)r * 512 + h] = (f16)(o * tanhfast(cn));
      outs[((size_t)r * 30 + s) * 512 + h] = (f16)o;
    }
}

// ---------------- fused lstm2 step ----------------
__global__ __launch_bounds__(256, 2) void k_l2step(const f16* __restrict__ hin, const f16* __restrict__ Whhp,
    const float* __restrict__ xi2, const float* __restrict__ cin, float* __restrict__ cout,
    f16* __restrict__ hout, float* __restrict__ l2o32, f16* __restrict__ l2o16, int ts) {
  __shared__ f16x8 sh[4096];
  const int rb = (blockIdx.x >> 4) * 128, cg = blockIdx.x & 15;
  f32x4 acc[4][4] = {};
  gemm_core(hin, Whhp, 512, rb, cg * 128, sh, acc);
  const int t = threadIdx.x, lane = t & 63, w = t >> 6;
  const int wr = (w >> 1) * 64, wc = (w & 1) * 64, ec = lane & 15, er = (lane >> 4) * 4;
  const int h = cg * 32 + (w & 1) * 16 + ec;
#pragma unroll
  for (int m = 0; m < 4; ++m)
#pragma unroll
    for (int j = 0; j < 4; ++j) {
      const int r = rb + wr + m * 16 + er + j;
      const size_t xb = ((size_t)r * 5 + ts) * 2048 + cg * 128 + wc + ec;
      const float p0 = acc[m][0][j] + xi2[xb];
      const float p1 = acc[m][1][j] + xi2[xb + 16];
      const float p2 = acc[m][2][j] + xi2[xb + 32];
      const float p3 = acc[m][3][j] + xi2[xb + 48];
      const float ii = sigf(p0), ff = sigf(p1), gg = tanhfast(p2), oo = sigf(p3);
      const float cn = ff * cin[(size_t)r * 512 + h] + ii * gg;
      const float hn = oo * tanhfast(cn);
      cout[(size_t)r * 512 + h] = cn;
      hout[(size_t)r * 512 + h] = (f16)hn;
      const size_t ob = ((size_t)r * 5 + ts) * 512 + h;
      l2o32[ob] = hn;
      l2o16[ob] = (f16)hn;
    }
}

// w1last[d] = A1_W1 @ outs[d, B-1, len-1] + b
__global__ __launch_bounds__(256) void k_w1last(const f16* __restrict__ outs, const int* __restrict__ lens,
                                                const float* __restrict__ W1, const float* __restrict__ W1b,
                                                float* __restrict__ w1l) {
  __shared__ float lastv[512];
  const int d = blockIdx.x;
  const int idx = lens[255 * 5 + d] - 1;
  const size_t row = ((size_t)(d * 256 + 255) * 30 + idx) * 512;
  for (int h = threadIdx.x; h < 512; h += 256) lastv[h] = (float)outs[row + h];
  __syncthreads();
  for (int h = threadIdx.x; h < 512; h += 256) {
    const float* wr = W1 + (size_t)h * 512;
    float p = W1b[h];
    for (int k = 0; k < 512; ++k) p += lastv[k] * wr[k];
    w1l[d * 512 + h] = p;
  }
}

// attn1 softmax + weighted sum
__global__ __launch_bounds__(256) void k_attn1(const float* __restrict__ score, const f16* __restrict__ outs,
                                               const int* __restrict__ lens,
                                               float* __restrict__ l1o32, f16* __restrict__ l1o16) {
  __shared__ float saw[32];
  const int n = blockIdx.x;
  const int d = n >> 8, b = n & 255;
  const int len = lens[b * 5 + d];
  const int t = threadIdx.x, lane = t & 63, w = t >> 6;
  if (w == 0) {
    const bool valid = lane < len;
    float sc = valid ? score[(size_t)n * 30 + lane] : -INFINITY;
    float mx = sc;
#pragma unroll
    for (int off = 32; off > 0; off >>= 1) mx = fmaxf(mx, __shfl_xor(mx, off));
    float e = valid ? __expf(sc - mx) : 0.f;
    float sm = e;
#pragma unroll
    for (int off = 32; off > 0; off >>= 1) sm += __shfl_xor(sm, off);
    if (lane < 30) saw[lane] = e / sm;
  }
  __syncthreads();
  for (int h = t; h < 512; h += 256) {
    float acc = 0.f;
    for (int s = 0; s < len; ++s) acc += saw[s] * (float)outs[((size_t)n * 30 + s) * 512 + h];
    const size_t o = ((size_t)b * 5 + d) * 512 + h;
    l1o32[o] = acc;
    l1o16[o] = (f16)acc;
  }
}

// merged u2/v2 GEMMs for attn2
__global__ __launch_bounds__(256, 2) void k_uv(const f16* __restrict__ l2o16, const f16* __restrict__ A2W2c,
    const f16* __restrict__ h2fin, const f16* __restrict__ A2W1c,
    const float* __restrict__ bu, const float* __restrict__ bv,
    float* __restrict__ u2, float* __restrict__ v2) {
  __shared__ f16x8 sh[4096];
  const int bid = blockIdx.x;
  const f16* A; const f16* B; const float* bias; float* out; int rb, cb;
  if (bid < 40) { A = l2o16; B = A2W2c; bias = bu; out = u2; rb = (bid >> 2) * 128; cb = (bid & 3) * 128; }
  else { int b2 = bid - 40; A = h2fin; B = A2W1c; bias = bv; out = v2; rb = (b2 >> 2) * 128; cb = (b2 & 3) * 128; }
  f32x4 acc[4][4] = {};
  gemm_core(A, B, 512, rb, cb, sh, acc);
  const int t = threadIdx.x, lane = t & 63, w = t >> 6;
  const int wr = (w >> 1) * 64, wc = (w & 1) * 64, ec = lane & 15, er = (lane >> 4) * 4;
#pragma unroll
  for (int m = 0; m < 4; ++m)
#pragma unroll
    for (int n = 0; n < 4; ++n) {
      const int c = cb + wc + n * 16 + ec;
      const float bvv = bias[c];
#pragma unroll
      for (int j = 0; j < 4; ++j) out[(size_t)(rb + wr + m * 16 + er + j) * 512 + c] = acc[m][n][j] + bvv;
    }
}

// attn2 over D=5 days
__global__ __launch_bounds__(256) void k_attn2(const float* __restrict__ u2, const float* __restrict__ v2,
                                               const float* __restrict__ l2o, const float* __restrict__ V2,
                                               const float* __restrict__ V2b, f16* __restrict__ ctx16) {
  __shared__ float ssc[8];
  __shared__ float saw[8];
  const int b = blockIdx.x;
  const int t = threadIdx.x, lane = t & 63, w = t >> 6;
  for (int tt = w; tt < 5; tt += 4) {
    const float* ur = u2 + ((size_t)b * 5 + tt) * 512;
    const float* vr = v2 + (size_t)b * 512;
    float p = 0.f;
#pragma unroll
    for (int j = 0; j < 8; ++j) { int h = lane * 8 + j; p += V2[h] * tanhfast(ur[h] + vr[h]); }
#pragma unroll
    for (int off = 32; off > 0; off >>= 1) p += __shfl_down(p, off);
    if (lane == 0) ssc[tt] = p + V2b[0];
  }
  __syncthreads();
  if (w == 0) {
    const bool valid = lane < 5;
    float sc = valid ? ssc[lane] : -INFINITY;
    float mx = sc;
#pragma unroll
    for (int off = 32; off > 0; off >>= 1) mx = fmaxf(mx, __shfl_xor(mx, off));
    float e = valid ? __expf(sc - mx) : 0.f;
    float sm = e;
#pragma unroll
    for (int off = 32; off > 0; off >>= 1) sm += __shfl_xor(sm, off);
    if (valid) saw[lane] = e / sm;
  }
  __syncthreads();
  for (int h = t; h < 512; h += 256) {
    float a = 0.f;
#pragma unroll
    for (int tt = 0; tt < 5; ++tt) a += saw[tt] * l2o[((size_t)b * 5 + tt) * 512 + h];
    ctx16[(size_t)b * 512 + h] = (f16)a;
  }
}

// final: out = h3 @ lin4^T + b4
__global__ __launch_bounds__(256) void k_final(const float* __restrict__ h3, const float* __restrict__ W4,
                                               const float* __restrict__ b4, float* __restrict__ out) {
  const int idx = blockIdx.x * 256 + threadIdx.x;
  const int b = idx >> 1, o = idx & 1;
  const float* hr = h3 + b * 256;
  const float* wr = W4 + o * 256;
  float p = b4[o];
  for (int j = 0; j < 256; ++j) p += hr[j] * wr[j];
  out[idx] = p;
}

// ---------------- prep kernels ----------------
// cast sentence_feats to s-major x16s[s][n][768], n = d*256+b
__global__ __launch_bounds__(256) void k_castx(const float* __restrict__ sf, f16* __restrict__ x16s) {
  const int total = 7372800;  // 38400*768/4
  for (int e = blockIdx.x * 256 + threadIdx.x; e < total; e += gridDim.x * 256) {
    const int row = e / 192, k = e - row * 192;
    const int b = row / 150, rem = row - b * 150;
    const int d = rem / 30, s = rem - d * 30;
    const int orow = s * 1280 + d * 256 + b;
    const float4 v = ((const float4*)sf)[e];
    f16x4 o = {(f16)v.x, (f16)v.y, (f16)v.z, (f16)v.w};
    ((f16x4*)x16s)[(size_t)orow * 192 + k] = o;
  }
}

// merged weight cast (+optional gate permutation)
struct WPArgs { const float* src[9]; f16* dst[9]; int k4[9]; int cnt4[9]; int perm[9]; };
__global__ __launch_bounds__(256) void k_castwp(WPArgs a) {
  int g = blockIdx.x * 256 + threadIdx.x;
#pragma unroll
  for (int si = 0; si < 9; ++si) {
    if (g < a.cnt4[si]) {
      const int K4 = a.k4[si];
      const int c = g / K4, k = g - c * K4;
      const int srow = a.perm[si] ? permrow(c) : c;
      const float4 v = ((const float4*)a.src[si])[(size_t)srow * K4 + k];
      f16x4 o = {(f16)v.x, (f16)v.y, (f16)v.z, (f16)v.w};
      ((f16x4*)a.dst[si])[(size_t)c * K4 + k] = o;
      return;
    }
    g -= a.cnt4[si];
  }
}

// state init + tft + score. PERSISTENT/FRESH regions ONLY — must NOT touch the x16s overlay
// (R8/R9 bug: zeroing h2/c2 here clobbered live x16s rows 9493-10352).
__global__ __launch_bounds__(256) void k_zero(f16* h16a, f16* c16a, float* c32a,
    float* ballp, float* bihp, const float* Wall_b, const float* Uall_b,
    const float* bih, const float* bhh, float* tft, const float* tf,
    float* score, const float* Vb) {
  const int i = blockIdx.x * 256 + threadIdx.x;
  if (i < 655360) { h16a[i] = (f16)0.f; c16a[i] = (f16)0.f; c32a[i] = 0.f; }
  if (i < 2048) {
    const int p = permrow(i);
    ballp[i] = Wall_b[p] + Uall_b[p];
    bihp[i] = bih[p] + bhh[p];
  }
  if (i < 38400) {
    const int s = i / 1280, r = i - s * 1280;
    const int d = r >> 8, b = r & 255;
    tft[i] = tf[((size_t)b * 5 + d) * 30 + s];
    score[i] = Vb[0];
  }
}

// lstm2 state init — runs AFTER the recurrence (x16s dead), h2/c2 live in the overlay region
__global__ __launch_bounds__(256) void k_init2(f16* h2a, float* c2a) {
  const int i = blockIdx.x * 256 + threadIdx.x;
  if (i < 131072) { h2a[i] = (f16)0.f; c2a[i] = 0.f; }
}

// ---------------- launch ----------------
extern "C" void kernel_launch(void* const* d_in, const int* in_sizes, int n_in,
                              void* d_out, int out_size, void* d_ws, size_t ws_size,
                              hipStream_t stream) {
  const float* sf     = (const float*)d_in[0];
  const float* tf     = (const float*)d_in[1];
  const int*   lens   = (const int*)d_in[2];
  const float* Wd_w   = (const float*)d_in[3];
  const float* Wd_b   = (const float*)d_in[4];
  const float* Wall_w = (const float*)d_in[5];
  const float* Wall_b = (const float*)d_in[6];
  const float* Uall_w = (const float*)d_in[7];
  const float* Uall_b = (const float*)d_in[8];
  const float* A1W1   = (const float*)d_in[9];
  const float* A1W1b  = (const float*)d_in[10];
  const float* A1W2   = (const float*)d_in[11];
  const float* A1W2b  = (const float*)d_in[12];
  const float* A1V    = (const float*)d_in[13];
  const float* A1Vb   = (const float*)d_in[14];
  const float* Wih    = (const float*)d_in[15];
  const float* Whh    = (const float*)d_in[16];
  const float* bih    = (const float*)d_in[17];
  const float* bhh    = (const float*)d_in[18];
  const float* A2W1   = (const float*)d_in[19];
  const float* A2W1b  = (const float*)d_in[20];
  const float* A2W2   = (const float*)d_in[21];
  const float* A2W2b  = (const float*)d_in[22];
  const float* A2V    = (const float*)d_in[23];
  const float* A2Vb   = (const float*)d_in[24];
  const float* L3w    = (const float*)d_in[25];
  const float* L3b    = (const float*)d_in[26];
  const float* L4w    = (const float*)d_in[27];
  const float* L4b    = (const float*)d_in[28];

  if (ws_size < WS_NEED) return;
  char* ws = (char*)d_ws;
  f16*   x16s   = (f16*)(ws + OFF_X16);
  f16*   ux16   = (f16*)(ws + OFF_UX);
  f16*   outs16 = (f16*)(ws + OFF_OUTS);
  f16*   Wd16   = (f16*)(ws + OFF_WD);
  f16*   Wallp  = (f16*)(ws + OFF_WALLP);
  f16*   U16p   = (f16*)(ws + OFF_UP);
  f16*   W216   = (f16*)(ws + OFF_W2);
  f16*   Wihp   = (f16*)(ws + OFF_WIHP);
  f16*   Whhp   = (f16*)(ws + OFF_WHHP);
  f16*   A2W116 = (f16*)(ws + OFF_A2W1C);
  f16*   A2W216 = (f16*)(ws + OFF_A2W2C);
  f16*   L316   = (f16*)(ws + OFF_L3WC);
  float* ballp  = (float*)(ws + OFF_BALLP);
  float* bihp   = (float*)(ws + OFF_BIHP);
  f16*   h16b[2]  = {(f16*)(ws + OFF_H16), (f16*)(ws + OFF_H16 + 1310720)};
  f16*   c16b[2]  = {(f16*)(ws + OFF_C16), (f16*)(ws + OFF_C16 + 1310720)};
  float* c32b[2]  = {(float*)(ws + OFF_C32), (float*)(ws + OFF_C32 + 2621440)};
  float* tft    = (float*)(ws + OFF_TFTN);
  float* score  = (float*)(ws + OFF_SCOREN);
  float* w1l    = (float*)(ws + OFF_W1L);
  float* l1o32  = (float*)(ws + OFF_L1O32);
  f16*   l1o16  = (f16*)(ws + OFF_L1O16);
  float* xi2    = (float*)(ws + OFF_XI2);
  float* c2b[2] = {(float*)(ws + OFF_C2), (float*)(ws + OFF_C2 + 524288)};
  f16*   h2b[2] = {(f16*)(ws + OFF_H2), (f16*)(ws + OFF_H2 + 262144)};
  float* l2o32  = (float*)(ws + OFF_L2O32);
  f16*   l2o16  = (f16*)(ws + OFF_L2O16);
  float* u2     = (float*)(ws + OFF_U2);
  float* v2     = (float*)(ws + OFF_V2);
  f16*   ctx16  = (f16*)(ws + OFF_CTX16);
  float* h3     = (float*)(ws + OFF_H3);

  // 1. input casts + init (k_zero touches ONLY persistent/fresh regions — x16s stays intact)
  k_castx<<<2048, 256, 0, stream>>>(sf, x16s);
  WPArgs wa;
  wa.src[0] = Wd_w;   wa.dst[0] = Wd16;   wa.k4[0] = 128; wa.cnt4[0] = 65536;  wa.perm[0] = 0;
  wa.src[1] = A1W2;   wa.dst[1] = W216;   wa.k4[1] = 128; wa.cnt4[1] = 65536;  wa.perm[1] = 0;
  wa.src[2] = A2W1;   wa.dst[2] = A2W116; wa.k4[2] = 128; wa.cnt4[2] = 65536;  wa.perm[2] = 0;
  wa.src[3] = A2W2;   wa.dst[3] = A2W216; wa.k4[3] = 128; wa.cnt4[3] = 65536;  wa.perm[3] = 0;
  wa.src[4] = L3w;    wa.dst[4] = L316;   wa.k4[4] = 128; wa.cnt4[4] = 32768;  wa.perm[4] = 0;
  wa.src[5] = Wall_w; wa.dst[5] = Wallp;  wa.k4[5] = 128; wa.cnt4[5] = 262144; wa.perm[5] = 1;
  wa.src[6] = Uall_w; wa.dst[6] = U16p;   wa.k4[6] = 192; wa.cnt4[6] = 393216; wa.perm[6] = 1;
  wa.src[7] = Wih;    wa.dst[7] = Wihp;   wa.k4[7] = 128; wa.cnt4[7] = 262144; wa.perm[7] = 1;
  wa.src[8] = Whh;    wa.dst[8] = Whhp;   wa.k4[8] = 128; wa.cnt4[8] = 262144; wa.perm[8] = 1;
  k_castwp<<<5760, 256, 0, stream>>>(wa);
  k_zero<<<2560, 256, 0, stream>>>(h16b[0], c16b[0], c32b[0], ballp, bihp, Wall_b, Uall_b, bih, bhh,
                                   tft, tf, score, A1Vb);

  // 2. ux prologue: slabs 0,1 (rows 0..2559 of s-major layout), 256^2 tiles
  k_gemm256<<<dim3(8, 10), 512, 0, stream>>>(x16s, U16p, 768, 2048, ux16);

  // 3. TimeLSTM recurrence: 30 launches; each carries the ux GEMM for slab s+2
  //    on the 96 CUs the 160-block step grid leaves idle.
  for (int s = 0; s < 30; ++s) {
    const int pi = s & 1, po = pi ^ 1;
    const int nb = (s <= 27) ? 320 : 160;
    k_stepm<<<nb, 256, 0, stream>>>(h16b[pi], c16b[pi], c32b[pi], Wallp, Wd16, ux16, ballp, Wd_b, tft,
                                    c32b[po], c16b[po], h16b[po], outs16,
                                    x16s, U16p, ux16, s);
  }

  // 4. lstm2 state init (x16s now dead; h2/c2 live in the overlay region)
  k_init2<<<512, 256, 0, stream>>>(h2b[0], c2b[0]);

  // 5. attn1 (score GEMM on the 128^2 core, 2 blocks/CU, 1200-block grid)
  k_w1last<<<5, 256, 0, stream>>>(outs16, lens, A1W1, A1W1b, w1l);
  k_score<<<dim3(4, 300), 256, 0, stream>>>(outs16, W216, A1W2b, w1l, A1V, score);
  k_attn1<<<1280, 256, 0, stream>>>(score, outs16, lens, l1o32, l1o16);

  // 6. lstm2: xi2 (permuted cols, biases folded), then 5 fused steps
  k_gemm<0, true, false><<<dim3(16, 10), 256, 0, stream>>>(l1o16, Wihp, 512, 2048, bihp, xi2, nullptr);
  for (int ts = 0; ts < 5; ++ts) {
    const int pi = ts & 1, po = pi ^ 1;
    k_l2step<<<32, 256, 0, stream>>>(h2b[pi], Whhp, xi2, c2b[pi], c2b[po], h2b[po], l2o32, l2o16, ts);
  }

  // 7. attn2 (h2 final is buffer 1 after 5 steps)
  k_uv<<<48, 256, 0, stream>>>(l2o16, A2W216, h2b[1], A2W116, A2W2b, A2W1b, u2, v2);
  k_attn2<<<256, 256, 0, stream>>>(u2, v2, l2o32, A2V, A2Vb, ctx16);

  // 8. head
  k_gemm<3, true, false><<<dim3(2, 2), 256, 0, stream>>>(ctx16, L316, 512, 256, L3b, h3, nullptr);
  k_final<<<2, 256, 0, stream>>>(h3, L4w, L4b, (float*)d_out);
}